// Round 8
// baseline (11410.551 us; speedup 1.0000x reference)
//
#include <hip/hip_runtime.h>
#include <math.h>

#define T 8
#define N 5000
#define E 160000
#define EN (E + N)
#define IN_DIM 64
#define HID 128
#define H 8
#define D 16
#define NC 2

// monotone float<->uint encoding for atomicMax on floats (0 == -inf sentinel)
__device__ __forceinline__ unsigned enc_f(float f) {
    unsigned b = __float_as_uint(f);
    return (b & 0x80000000u) ? ~b : (b | 0x80000000u);
}
__device__ __forceinline__ float dec_f(unsigned u) {
    unsigned b = (u & 0x80000000u) ? (u & 0x7FFFFFFFu) : ~u;
    return __uint_as_float(b);
}

__global__ void k_proj(const float* __restrict__ x_t, const float* __restrict__ Wp,
                       const float* __restrict__ bp, float* __restrict__ h_t) {
    int idx = blockIdx.x * 256 + threadIdx.x;
    int c = idx & (HID - 1);
    int r = idx >> 7;
    const float* xr = x_t + (size_t)r * IN_DIM;
    float acc = bp[c];
    for (int k = 0; k < IN_DIM; ++k)
        acc += xr[k] * Wp[k * HID + c];
    h_t[idx] = fmaxf(acc, 0.0f);
}

__global__ void k_gat(const float* __restrict__ h_t, const float* __restrict__ Wg,
                      float* __restrict__ xh_t) {
    int idx = blockIdx.x * 256 + threadIdx.x;
    int c = idx & (HID - 1);
    int r = idx >> 7;
    const float* hr = h_t + (size_t)r * HID;
    float acc = 0.0f;
    for (int k = 0; k < HID; ++k)
        acc += hr[k] * Wg[k * HID + c];
    xh_t[idx] = acc;
}

__global__ void k_coef(const float* __restrict__ xh_t, const float* __restrict__ asrc,
                       const float* __restrict__ adst, float* __restrict__ as_t,
                       float* __restrict__ ad_t) {
    int idx = blockIdx.x * 256 + threadIdx.x;
    if (idx >= N * H) return;
    int hh = idx & (H - 1);
    int r  = idx >> 3;
    const float* row = xh_t + (size_t)r * HID + hh * D;
    float s1 = 0.0f, s2 = 0.0f;
    for (int d = 0; d < D; ++d) {
        s1 += row[d] * asrc[hh * D + d];
        s2 += row[d] * adst[hh * D + d];
    }
    as_t[idx] = s1;
    ad_t[idx] = s2;
}

__device__ __forceinline__ void esd(const int* __restrict__ ei_s, const int* __restrict__ ei_d,
                                    int i, int& s, int& d) {
    if (i < E) { s = ei_s[i]; d = ei_d[i]; }
    else       { s = d = i - E; }
}
__device__ __forceinline__ float leaky(float e) { return (e >= 0.0f) ? e : 0.2f * e; }

__global__ void k_emax(const int* __restrict__ ei_s, const int* __restrict__ ei_d,
                       const float* __restrict__ as_t, const float* __restrict__ ad_t,
                       unsigned* __restrict__ m_t) {
    int idx = blockIdx.x * 256 + threadIdx.x;
    if (idx >= EN * H) return;
    int hh = idx & (H - 1);
    int i  = idx >> 3;
    int s, d;
    esd(ei_s, ei_d, i, s, d);
    float e = leaky(as_t[s * H + hh] + ad_t[d * H + hh]);
    atomicMax(&m_t[d * H + hh], enc_f(e));
}

__global__ void k_esum(const int* __restrict__ ei_s, const int* __restrict__ ei_d,
                       const float* __restrict__ as_t, const float* __restrict__ ad_t,
                       const unsigned* __restrict__ m_t, float* __restrict__ s_t) {
    int idx = blockIdx.x * 256 + threadIdx.x;
    if (idx >= EN * H) return;
    int hh = idx & (H - 1);
    int i  = idx >> 3;
    int s, d;
    esd(ei_s, ei_d, i, s, d);
    float e = leaky(as_t[s * H + hh] + ad_t[d * H + hh]);
    atomicAdd(&s_t[d * H + hh], expf(e - dec_f(m_t[d * H + hh])));
}

__global__ void k_eagg(const int* __restrict__ ei_s, const int* __restrict__ ei_d,
                       const float* __restrict__ as_t, const float* __restrict__ ad_t,
                       const unsigned* __restrict__ m_t, const float* __restrict__ s_t,
                       const float* __restrict__ xh_t, float* __restrict__ gout_t) {
    int idx = blockIdx.x * 256 + threadIdx.x;
    if (idx >= EN * H) return;
    int hh = idx & (H - 1);
    int i  = idx >> 3;
    int s, d;
    esd(ei_s, ei_d, i, s, d);
    float e = leaky(as_t[s * H + hh] + ad_t[d * H + hh]);
    float ex = expf(e - dec_f(m_t[d * H + hh]));
    float alpha = ex / (s_t[d * H + hh] + 1e-16f);
    const float* xrow = xh_t + (size_t)s * HID + hh * D;
    float* grow = gout_t + (size_t)d * HID + hh * D;
    for (int dd = 0; dd < D; ++dd)
        atomicAdd(&grow[dd], xrow[dd] * alpha);
}

__global__ void k_ln1(const float* __restrict__ gout, const float* __restrict__ b_gat,
                      const float* __restrict__ g1, const float* __restrict__ be1,
                      float* __restrict__ nrmg) {
    int idx = blockIdx.x * 256 + threadIdx.x;
    if (idx >= N * T) return;
    int t = idx & (T - 1);
    int n = idx >> 3;
    const float* src = gout + (size_t)(t * N + n) * HID;
    float mu = 0.0f;
    for (int c = 0; c < HID; ++c) mu += src[c] + b_gat[c];
    mu *= (1.0f / HID);
    float var = 0.0f;
    for (int c = 0; c < HID; ++c) {
        float dv = src[c] + b_gat[c] - mu;
        var += dv * dv;
    }
    float rstd = rsqrtf(var * (1.0f / HID) + 1e-5f);
    float* dst = nrmg + (size_t)(n * T + t) * HID;
    for (int c = 0; c < HID; ++c)
        dst[c] = (src[c] + b_gat[c] - mu) * rstd * g1[c] + be1[c];
}

__global__ void k_att(const float* __restrict__ nrmg, const float* __restrict__ W_qkv,
                      const float* __restrict__ b_qkv, float* __restrict__ tag) {
    int idx = blockIdx.x * 256 + threadIdx.x;
    if (idx >= N * H) return;
    int h = idx & (H - 1);
    int n = idx >> 3;
    const float* nr = nrmg + (size_t)n * T * HID;

    float q[D];
    for (int dd = 0; dd < D; ++dd) {
        int j = h * D + dd;
        float acc = b_qkv[j];
        const float* w = W_qkv + (size_t)j * HID;
        const float* v = nr + (size_t)(T - 1) * HID;
        for (int c = 0; c < HID; ++c) acc += v[c] * w[c];
        q[dd] = acc;
    }
    float sc[T];
    float mx = -1e30f;
    for (int tk = 0; tk < T; ++tk) {
        float dot = 0.0f;
        for (int dd = 0; dd < D; ++dd) {
            int j = HID + h * D + dd;
            float acc = b_qkv[j];
            const float* w = W_qkv + (size_t)j * HID;
            const float* v = nr + (size_t)tk * HID;
            for (int c = 0; c < HID; ++c) acc += v[c] * w[c];
            dot += q[dd] * acc;
        }
        sc[tk] = dot * 0.25f;
        mx = fmaxf(mx, sc[tk]);
    }
    float ssum = 0.0f;
    for (int tk = 0; tk < T; ++tk) { sc[tk] = expf(sc[tk] - mx); ssum += sc[tk]; }
    float inv = 1.0f / ssum;

    float ta[D];
    for (int dd = 0; dd < D; ++dd) ta[dd] = 0.0f;
    for (int tk = 0; tk < T; ++tk) {
        float a = sc[tk] * inv;
        for (int dd = 0; dd < D; ++dd) {
            int j = 2 * HID + h * D + dd;
            float acc = b_qkv[j];
            const float* w = W_qkv + (size_t)j * HID;
            const float* v = nr + (size_t)tk * HID;
            for (int c = 0; c < HID; ++c) acc += v[c] * w[c];
            ta[dd] += a * acc;
        }
    }
    for (int dd = 0; dd < D; ++dd)
        tag[(size_t)n * HID + h * D + dd] = ta[dd];
}

__global__ void k_wo(const float* __restrict__ tag, const float* __restrict__ W_o,
                     const float* __restrict__ b_o, const float* __restrict__ gout,
                     const float* __restrict__ b_gat, float* __restrict__ x2g) {
    int idx = blockIdx.x * 256 + threadIdx.x;
    int j = idx & (HID - 1);
    int n = idx >> 7;
    const float* tr = tag + (size_t)n * HID;
    const float* w  = W_o + (size_t)j * HID;
    float o = b_o[j];
    for (int k = 0; k < HID; ++k) o += tr[k] * w[k];
    x2g[idx] = gout[(size_t)((T - 1) * N + n) * HID + j] + b_gat[j] + o;
}

// LN2 + div + noise -> embg + OUT (FLOAT32 output!)
__global__ void k_ln2emb(const float* __restrict__ x2g, const float* __restrict__ g2,
                         const float* __restrict__ be2, const float* __restrict__ noise,
                         float* __restrict__ embg, float* __restrict__ out) {
    int n = blockIdx.x * 256 + threadIdx.x;
    if (n >= N) return;
    const float* xr = x2g + (size_t)n * HID;
    float mu = 0.0f;
    for (int c = 0; c < HID; ++c) mu += xr[c];
    mu *= (1.0f / HID);
    float var = 0.0f;
    for (int c = 0; c < HID; ++c) { float dv = xr[c] - mu; var += dv * dv; }
    float rstd = rsqrtf(var * (1.0f / HID) + 1e-5f);
    float div = sinf(((float)n / (float)N) * 6.28f) * 0.1f;
    for (int c = 0; c < HID; ++c) {
        float e = (xr[c] - mu) * rstd * g2[c] + be2[c]
                + div + noise[(size_t)n * HID + c] * 0.05f;
        embg[(size_t)n * HID + c] = e;
        out[(size_t)n * HID + c] = e;           // f32 store
    }
}

__global__ void k_h1(const float* __restrict__ embg, const float* __restrict__ Wc1,
                     const float* __restrict__ bc1, float* __restrict__ h1g) {
    int idx = blockIdx.x * 256 + threadIdx.x;
    int j = idx & (HID - 1);
    int n = idx >> 7;
    const float* er = embg + (size_t)n * HID;
    float acc = bc1[j];
    for (int c = 0; c < HID; ++c) acc += er[c] * Wc1[c * HID + j];
    h1g[idx] = acc;
}

__global__ void k_ln3g(float* __restrict__ h1g, const float* __restrict__ gc,
                       const float* __restrict__ bec) {
    int n = blockIdx.x * 256 + threadIdx.x;
    if (n >= N) return;
    float* r = h1g + (size_t)n * HID;
    float mu = 0.0f;
    for (int c = 0; c < HID; ++c) mu += r[c];
    mu *= (1.0f / HID);
    float var = 0.0f;
    for (int c = 0; c < HID; ++c) { float dv = r[c] - mu; var += dv * dv; }
    float rstd = rsqrtf(var * (1.0f / HID) + 1e-5f);
    for (int c = 0; c < HID; ++c) {
        float lnv = (r[c] - mu) * rstd * gc[c] + bec[c];
        r[c] = 0.5f * lnv * (1.0f + erff(lnv * 0.70710678118f));
    }
}

// logits (FLOAT32 output)
__global__ void k_logits(const float* __restrict__ h1g, const float* __restrict__ Wc2,
                         const float* __restrict__ bc2, float* __restrict__ out) {
    int idx = blockIdx.x * 256 + threadIdx.x;
    if (idx >= N * NC) return;
    int j = idx & (NC - 1);
    int n = idx >> 1;
    const float* r = h1g + (size_t)n * HID;
    float acc = bc2[j];
    for (int c = 0; c < HID; ++c) acc += r[c] * Wc2[c * NC + j];
    if (j == 1) acc += sinf((float)n * 0.5f) * 0.2f;
    out[(size_t)N * HID + (size_t)n * NC + j] = acc;   // f32 store
}

extern "C" void kernel_launch(void* const* d_in, const int* in_sizes, int n_in,
                              void* d_out, int out_size, void* d_ws, size_t ws_size,
                              hipStream_t stream) {
    const float* x      = (const float*)d_in[0];
    const int*   ei     = (const int*)d_in[1];
    const float* noise  = (const float*)d_in[2];
    const float* W_proj = (const float*)d_in[3];
    const float* b_proj = (const float*)d_in[4];
    const float* W_gat  = (const float*)d_in[5];
    const float* a_src  = (const float*)d_in[6];
    const float* a_dst  = (const float*)d_in[7];
    const float* b_gat  = (const float*)d_in[8];
    const float* g1     = (const float*)d_in[9];
    const float* be1    = (const float*)d_in[10];
    const float* W_qkv  = (const float*)d_in[11];
    const float* b_qkv  = (const float*)d_in[12];
    const float* W_o    = (const float*)d_in[13];
    const float* b_o    = (const float*)d_in[14];
    const float* g2     = (const float*)d_in[15];
    const float* be2    = (const float*)d_in[16];
    const float* Wc1    = (const float*)d_in[17];
    const float* bc1    = (const float*)d_in[18];
    const float* gc     = (const float*)d_in[19];
    const float* bec    = (const float*)d_in[20];
    const float* Wc2    = (const float*)d_in[21];
    const float* bc2    = (const float*)d_in[22];
    float* out = (float*)d_out;                        // FLOAT32 output

    float*    gout = (float*)d_ws;
    float*    h_t  = gout + 5120000;
    float*    xh_t = h_t  + 640000;
    float*    a_s  = xh_t + 640000;
    float*    a_d  = a_s  + 320000;
    unsigned* m    = (unsigned*)(a_d + 320000);
    float*    s    = (float*)(m + 320000);
    float*    nrmg = s + 320000;
    float*    tag  = nrmg + 5120000;
    float*    x2g  = tag  + 640000;
    float*    embg = x2g  + 640000;
    float*    h1g  = embg + 640000;

    hipMemsetAsync(gout, 0, 5120000ull * 4, stream);
    hipMemsetAsync(m, 0, 640000ull * 4, stream);

    for (int t = 0; t < T; ++t) {
        const float* x_t = x + (size_t)t * N * IN_DIM;
        const int* ei_s  = ei + (size_t)(2 * t) * E;
        const int* ei_d  = ei + (size_t)(2 * t + 1) * E;
        float* as_t      = a_s + (size_t)t * N * H;
        float* ad_t      = a_d + (size_t)t * N * H;
        unsigned* m_t    = m   + (size_t)t * N * H;
        float* s_t       = s   + (size_t)t * N * H;
        float* gout_t    = gout + (size_t)t * N * HID;

        k_proj<<<N * HID / 256, 256, 0, stream>>>(x_t, W_proj, b_proj, h_t);
        k_gat<<<N * HID / 256, 256, 0, stream>>>(h_t, W_gat, xh_t);
        k_coef<<<(N * H + 255) / 256, 256, 0, stream>>>(xh_t, a_src, a_dst, as_t, ad_t);
        k_emax<<<(EN * H + 255) / 256, 256, 0, stream>>>(ei_s, ei_d, as_t, ad_t, m_t);
        k_esum<<<(EN * H + 255) / 256, 256, 0, stream>>>(ei_s, ei_d, as_t, ad_t, m_t, s_t);
        k_eagg<<<(EN * H + 255) / 256, 256, 0, stream>>>(ei_s, ei_d, as_t, ad_t, m_t, s_t, xh_t, gout_t);
    }

    k_ln1<<<(N * T + 255) / 256, 256, 0, stream>>>(gout, b_gat, g1, be1, nrmg);
    k_att<<<(N * H + 255) / 256, 256, 0, stream>>>(nrmg, W_qkv, b_qkv, tag);
    k_wo<<<N * HID / 256, 256, 0, stream>>>(tag, W_o, b_o, gout, b_gat, x2g);
    k_ln2emb<<<(N + 255) / 256, 256, 0, stream>>>(x2g, g2, be2, noise, embg, out);
    k_h1<<<N * HID / 256, 256, 0, stream>>>(embg, Wc1, bc1, h1g);
    k_ln3g<<<(N + 255) / 256, 256, 0, stream>>>(h1g, gc, bec);
    k_logits<<<(N * NC + 255) / 256, 256, 0, stream>>>(h1g, Wc2, bc2, out);
}

// Round 9
// 1871.411 us; speedup vs baseline: 6.0973x; 6.0973x over previous
//
#include <hip/hip_runtime.h>
#include <math.h>

#define T 8
#define N 5000
#define E 160000
#define EN (E + N)
#define IN_DIM 64
#define HID 128
#define H 8
#define D 16
#define NC 2

__device__ __forceinline__ float leaky(float e) { return (e >= 0.0f) ? e : 0.2f * e; }

// h = relu(x @ W_proj + b_proj)  (all t)
__global__ void k_proj(const float* __restrict__ x, const float* __restrict__ Wp,
                       const float* __restrict__ bp, float* __restrict__ h) {
    int idx = blockIdx.x * 256 + threadIdx.x;      // < T*N*HID exact
    int c = idx & (HID - 1);
    int r = idx >> 7;
    const float* xr = x + (size_t)r * IN_DIM;
    float acc = bp[c];
    for (int k = 0; k < IN_DIM; ++k)
        acc += xr[k] * Wp[k * HID + c];
    h[idx] = fmaxf(acc, 0.0f);
}

// xh = h @ W_gat  (all t)
__global__ void k_gat(const float* __restrict__ h, const float* __restrict__ Wg,
                      float* __restrict__ xh) {
    int idx = blockIdx.x * 256 + threadIdx.x;      // < T*N*HID exact
    int c = idx & (HID - 1);
    int r = idx >> 7;
    const float* hr = h + (size_t)r * HID;
    float acc = 0.0f;
    for (int k = 0; k < HID; ++k)
        acc += hr[k] * Wg[k * HID + c];
    xh[idx] = acc;
}

// a_s/a_d  (all t)
__global__ void k_coef(const float* __restrict__ xh, const float* __restrict__ asrc,
                       const float* __restrict__ adst, float* __restrict__ a_s,
                       float* __restrict__ a_d) {
    int idx = blockIdx.x * 256 + threadIdx.x;
    if (idx >= T * N * H) return;
    int hh = idx & (H - 1);
    int r  = idx >> 3;
    const float* row = xh + (size_t)r * HID + hh * D;
    float s1 = 0.0f, s2 = 0.0f;
    for (int d = 0; d < D; ++d) {
        s1 += row[d] * asrc[hh * D + d];
        s2 += row[d] * adst[hh * D + d];
    }
    a_s[idx] = s1;
    a_d[idx] = s2;
}

__device__ __forceinline__ void esd_g(const int* __restrict__ ei, int t, int i,
                                      int& s, int& d) {
    if (i < E) {
        s = ei[(size_t)(2 * t) * E + i];
        d = ei[(size_t)(2 * t + 1) * E + i];
    } else {
        s = d = i - E;
    }
}

// histogram of dst per t  (cursor pre-zeroed)
__global__ void k_hist(const int* __restrict__ ei, int* __restrict__ cursor) {
    int idx = blockIdx.x * 256 + threadIdx.x;
    if (idx >= T * EN) return;
    int t = idx / EN;
    int i = idx - t * EN;
    int s, d;
    esd_g(ei, t, i, s, d);
    atomicAdd(&cursor[t * N + d], 1);
}

// per-t exclusive scan: counts(cursor) -> offs[t*(N+1)+*]; cursor := prefix (scatter cursors)
__global__ void k_scan(int* __restrict__ cursor, int* __restrict__ offs) {
    __shared__ int part[256];
    int t = blockIdx.x;
    int tid = threadIdx.x;
    const int CH = 20;                              // 256*20 >= 5000
    int begin = tid * CH;
    int sum = 0;
    for (int k = 0; k < CH; ++k) {
        int i = begin + k;
        if (i < N) sum += cursor[t * N + i];
    }
    part[tid] = sum;
    __syncthreads();
    if (tid == 0) {
        int run = 0;
        for (int i = 0; i < 256; ++i) { int v = part[i]; part[i] = run; run += v; }
        offs[t * (N + 1) + N] = run;                // == EN
    }
    __syncthreads();
    int run = part[tid];
    for (int k = 0; k < CH; ++k) {
        int i = begin + k;
        if (i < N) {
            int cnt = cursor[t * N + i];
            offs[t * (N + 1) + i] = run;
            cursor[t * N + i] = run;                // scatter cursor
            run += cnt;
        }
    }
}

__global__ void k_scatter(const int* __restrict__ ei, int* __restrict__ cursor,
                          int* __restrict__ csr_src) {
    int idx = blockIdx.x * 256 + threadIdx.x;
    if (idx >= T * EN) return;
    int t = idx / EN;
    int i = idx - t * EN;
    int s, d;
    esd_g(ei, t, i, s, d);
    int pos = atomicAdd(&cursor[t * N + d], 1);
    csr_src[(size_t)t * EN + pos] = s;
}

// GAT softmax + aggregation, one block per (t,dst), atomic-free
__global__ __launch_bounds__(128) void k_aggc(
        const int* __restrict__ offs, const int* __restrict__ csr_src,
        const float* __restrict__ a_s, const float* __restrict__ a_d,
        const float* __restrict__ xh, float* __restrict__ gout) {
    int b = blockIdx.x;                  // t*N + dst
    int t = b / N;
    int dst = b - t * N;
    int tid = threadIdx.x;

    int o0 = offs[t * (N + 1) + dst];
    int o1 = offs[t * (N + 1) + dst + 1];
    int deg = o1 - o0;
    const int* esrc = csr_src + (size_t)t * EN + o0;
    const float* as_b = a_s + (size_t)t * N * H;
    const float* ad_b = a_d + (size_t)t * N * H;
    const float* xh_b = xh + (size_t)t * N * HID;

    __shared__ float lm[H][16], ls[H][16];
    __shared__ float fm[H], finv[H];
    __shared__ float lal[16][H];
    __shared__ int   lsrc[16];

    // phase A: online (m,s) per head, 16 lanes/head
    {
        int ha = tid & 7, l = tid >> 3;
        float ad_h = ad_b[dst * H + ha];
        float m = -1e30f, ssum = 0.0f;
        for (int i = l; i < deg; i += 16) {
            int src = esrc[i];
            float e = leaky(as_b[src * H + ha] + ad_h);
            if (e > m) { ssum = ssum * expf(m - e) + 1.0f; m = e; }
            else       { ssum += expf(e - m); }
        }
        lm[ha][l] = m;
        ls[ha][l] = ssum;
    }
    __syncthreads();
    if (tid < H) {
        float mm = -1e30f;
        for (int l = 0; l < 16; ++l) mm = fmaxf(mm, lm[tid][l]);
        float ss = 0.0f;
        for (int l = 0; l < 16; ++l) ss += ls[tid][l] * expf(lm[tid][l] - mm);
        fm[tid] = mm;
        finv[tid] = 1.0f / (ss + 1e-16f);
    }
    __syncthreads();

    // phase B: chunked alpha + accumulate (thread = channel)
    int h = tid >> 4;
    int eh_e = tid >> 3, eh_h = tid & 7;
    float acc = 0.0f;
    for (int base = 0; base < deg; base += 16) {
        int ej = base + eh_e;
        if (ej < deg) {
            int src = esrc[ej];
            if (eh_h == 0) lsrc[eh_e] = src;
            float e = leaky(as_b[src * H + eh_h] + ad_b[dst * H + eh_h]);
            lal[eh_e][eh_h] = expf(e - fm[eh_h]) * finv[eh_h];
        }
        __syncthreads();
        int lim = min(16, deg - base);
        for (int j = 0; j < lim; ++j)
            acc += lal[j][h] * xh_b[(size_t)lsrc[j] * HID + tid];
        __syncthreads();
    }
    gout[(size_t)b * HID + tid] = acc;
}

__global__ void k_ln1(const float* __restrict__ gout, const float* __restrict__ b_gat,
                      const float* __restrict__ g1, const float* __restrict__ be1,
                      float* __restrict__ nrmg) {
    int idx = blockIdx.x * 256 + threadIdx.x;
    if (idx >= N * T) return;
    int t = idx & (T - 1);
    int n = idx >> 3;
    const float* src = gout + (size_t)(t * N + n) * HID;
    float mu = 0.0f;
    for (int c = 0; c < HID; ++c) mu += src[c] + b_gat[c];
    mu *= (1.0f / HID);
    float var = 0.0f;
    for (int c = 0; c < HID; ++c) {
        float dv = src[c] + b_gat[c] - mu;
        var += dv * dv;
    }
    float rstd = rsqrtf(var * (1.0f / HID) + 1e-5f);
    float* dst = nrmg + (size_t)(n * T + t) * HID;
    for (int c = 0; c < HID; ++c)
        dst[c] = (src[c] + b_gat[c] - mu) * rstd * g1[c] + be1[c];
}

__global__ void k_att(const float* __restrict__ nrmg, const float* __restrict__ W_qkv,
                      const float* __restrict__ b_qkv, float* __restrict__ tag) {
    int idx = blockIdx.x * 256 + threadIdx.x;
    if (idx >= N * H) return;
    int h = idx & (H - 1);
    int n = idx >> 3;
    const float* nr = nrmg + (size_t)n * T * HID;

    float q[D];
    for (int dd = 0; dd < D; ++dd) {
        int j = h * D + dd;
        float acc = b_qkv[j];
        const float* w = W_qkv + (size_t)j * HID;
        const float* v = nr + (size_t)(T - 1) * HID;
        for (int c = 0; c < HID; ++c) acc += v[c] * w[c];
        q[dd] = acc;
    }
    float sc[T];
    float mx = -1e30f;
    for (int tk = 0; tk < T; ++tk) {
        float dot = 0.0f;
        for (int dd = 0; dd < D; ++dd) {
            int j = HID + h * D + dd;
            float acc = b_qkv[j];
            const float* w = W_qkv + (size_t)j * HID;
            const float* v = nr + (size_t)tk * HID;
            for (int c = 0; c < HID; ++c) acc += v[c] * w[c];
            dot += q[dd] * acc;
        }
        sc[tk] = dot * 0.25f;
        mx = fmaxf(mx, sc[tk]);
    }
    float ssum = 0.0f;
    for (int tk = 0; tk < T; ++tk) { sc[tk] = expf(sc[tk] - mx); ssum += sc[tk]; }
    float inv = 1.0f / ssum;

    float ta[D];
    for (int dd = 0; dd < D; ++dd) ta[dd] = 0.0f;
    for (int tk = 0; tk < T; ++tk) {
        float a = sc[tk] * inv;
        for (int dd = 0; dd < D; ++dd) {
            int j = 2 * HID + h * D + dd;
            float acc = b_qkv[j];
            const float* w = W_qkv + (size_t)j * HID;
            const float* v = nr + (size_t)tk * HID;
            for (int c = 0; c < HID; ++c) acc += v[c] * w[c];
            ta[dd] += a * acc;
        }
    }
    for (int dd = 0; dd < D; ++dd)
        tag[(size_t)n * HID + h * D + dd] = ta[dd];
}

__global__ void k_wo(const float* __restrict__ tag, const float* __restrict__ W_o,
                     const float* __restrict__ b_o, const float* __restrict__ gout,
                     const float* __restrict__ b_gat, float* __restrict__ x2g) {
    int idx = blockIdx.x * 256 + threadIdx.x;
    int j = idx & (HID - 1);
    int n = idx >> 7;
    const float* tr = tag + (size_t)n * HID;
    const float* w  = W_o + (size_t)j * HID;
    float o = b_o[j];
    for (int k = 0; k < HID; ++k) o += tr[k] * w[k];
    x2g[idx] = gout[(size_t)((T - 1) * N + n) * HID + j] + b_gat[j] + o;
}

__global__ void k_ln2emb(const float* __restrict__ x2g, const float* __restrict__ g2,
                         const float* __restrict__ be2, const float* __restrict__ noise,
                         float* __restrict__ embg, float* __restrict__ out) {
    int n = blockIdx.x * 256 + threadIdx.x;
    if (n >= N) return;
    const float* xr = x2g + (size_t)n * HID;
    float mu = 0.0f;
    for (int c = 0; c < HID; ++c) mu += xr[c];
    mu *= (1.0f / HID);
    float var = 0.0f;
    for (int c = 0; c < HID; ++c) { float dv = xr[c] - mu; var += dv * dv; }
    float rstd = rsqrtf(var * (1.0f / HID) + 1e-5f);
    float div = sinf(((float)n / (float)N) * 6.28f) * 0.1f;
    for (int c = 0; c < HID; ++c) {
        float e = (xr[c] - mu) * rstd * g2[c] + be2[c]
                + div + noise[(size_t)n * HID + c] * 0.05f;
        embg[(size_t)n * HID + c] = e;
        out[(size_t)n * HID + c] = e;
    }
}

__global__ void k_h1(const float* __restrict__ embg, const float* __restrict__ Wc1,
                     const float* __restrict__ bc1, float* __restrict__ h1g) {
    int idx = blockIdx.x * 256 + threadIdx.x;
    int j = idx & (HID - 1);
    int n = idx >> 7;
    const float* er = embg + (size_t)n * HID;
    float acc = bc1[j];
    for (int c = 0; c < HID; ++c) acc += er[c] * Wc1[c * HID + j];
    h1g[idx] = acc;
}

__global__ void k_ln3g(float* __restrict__ h1g, const float* __restrict__ gc,
                       const float* __restrict__ bec) {
    int n = blockIdx.x * 256 + threadIdx.x;
    if (n >= N) return;
    float* r = h1g + (size_t)n * HID;
    float mu = 0.0f;
    for (int c = 0; c < HID; ++c) mu += r[c];
    mu *= (1.0f / HID);
    float var = 0.0f;
    for (int c = 0; c < HID; ++c) { float dv = r[c] - mu; var += dv * dv; }
    float rstd = rsqrtf(var * (1.0f / HID) + 1e-5f);
    for (int c = 0; c < HID; ++c) {
        float lnv = (r[c] - mu) * rstd * gc[c] + bec[c];
        r[c] = 0.5f * lnv * (1.0f + erff(lnv * 0.70710678118f));
    }
}

__global__ void k_logits(const float* __restrict__ h1g, const float* __restrict__ Wc2,
                         const float* __restrict__ bc2, float* __restrict__ out) {
    int idx = blockIdx.x * 256 + threadIdx.x;
    if (idx >= N * NC) return;
    int j = idx & (NC - 1);
    int n = idx >> 1;
    const float* r = h1g + (size_t)n * HID;
    float acc = bc2[j];
    for (int c = 0; c < HID; ++c) acc += r[c] * Wc2[c * NC + j];
    if (j == 1) acc += sinf((float)n * 0.5f) * 0.2f;
    out[(size_t)N * HID + (size_t)n * NC + j] = acc;
}

extern "C" void kernel_launch(void* const* d_in, const int* in_sizes, int n_in,
                              void* d_out, int out_size, void* d_ws, size_t ws_size,
                              hipStream_t stream) {
    const float* x      = (const float*)d_in[0];
    const int*   ei     = (const int*)d_in[1];
    const float* noise  = (const float*)d_in[2];
    const float* W_proj = (const float*)d_in[3];
    const float* b_proj = (const float*)d_in[4];
    const float* W_gat  = (const float*)d_in[5];
    const float* a_src  = (const float*)d_in[6];
    const float* a_dst  = (const float*)d_in[7];
    const float* b_gat  = (const float*)d_in[8];
    const float* g1     = (const float*)d_in[9];
    const float* be1    = (const float*)d_in[10];
    const float* W_qkv  = (const float*)d_in[11];
    const float* b_qkv  = (const float*)d_in[12];
    const float* W_o    = (const float*)d_in[13];
    const float* b_o    = (const float*)d_in[14];
    const float* g2     = (const float*)d_in[15];
    const float* be2    = (const float*)d_in[16];
    const float* Wc1    = (const float*)d_in[17];
    const float* bc1    = (const float*)d_in[18];
    const float* gc     = (const float*)d_in[19];
    const float* bec    = (const float*)d_in[20];
    const float* Wc2    = (const float*)d_in[21];
    const float* bc2    = (const float*)d_in[22];
    float* out = (float*)d_out;

    // workspace layout (51.7 MB, within proven >=61.44 MB):
    float* xh    = (float*)d_ws;                 // 5,120,000  (later: nrmg alias)
    float* gout  = xh + 5120000;                 // 5,120,000  (h alias before agg)
    float* a_s   = gout + 5120000;               //   320,000
    float* a_d   = a_s + 320000;                 //   320,000  (a_s..a_d later: x2g)
    float* tag   = a_d + 320000;                 //   640,000
    int*   offs    = (int*)(tag + 640000);       //    40,008
    int*   cursor  = offs + 40008;               //    40,000
    int*   csr_src = cursor + 40000;             // 1,320,000  (later: embg | h1g)

    float* h    = gout;                          // alias: h lives in gout space pre-agg
    float* nrmg = xh;                            // alias: after agg, xh dead
    float* x2g  = a_s;                           // alias: after agg, a_s/a_d dead
    float* embg = (float*)csr_src;               // alias: after agg
    float* h1g  = embg + 640000;

    k_proj<<<T * N * HID / 256, 256, 0, stream>>>(x, W_proj, b_proj, h);
    k_gat<<<T * N * HID / 256, 256, 0, stream>>>(h, W_gat, xh);
    k_coef<<<(T * N * H + 255) / 256, 256, 0, stream>>>(xh, a_src, a_dst, a_s, a_d);

    hipMemsetAsync(cursor, 0, 40000 * sizeof(int), stream);
    k_hist<<<(T * EN + 255) / 256, 256, 0, stream>>>(ei, cursor);
    k_scan<<<T, 256, 0, stream>>>(cursor, offs);
    k_scatter<<<(T * EN + 255) / 256, 256, 0, stream>>>(ei, cursor, csr_src);

    k_aggc<<<T * N, 128, 0, stream>>>(offs, csr_src, a_s, a_d, xh, gout);

    k_ln1<<<(N * T + 255) / 256, 256, 0, stream>>>(gout, b_gat, g1, be1, nrmg);
    k_att<<<(N * H + 255) / 256, 256, 0, stream>>>(nrmg, W_qkv, b_qkv, tag);
    k_wo<<<N * HID / 256, 256, 0, stream>>>(tag, W_o, b_o, gout, b_gat, x2g);
    k_ln2emb<<<(N + 255) / 256, 256, 0, stream>>>(x2g, g2, be2, noise, embg, out);
    k_h1<<<N * HID / 256, 256, 0, stream>>>(embg, Wc1, bc1, h1g);
    k_ln3g<<<(N + 255) / 256, 256, 0, stream>>>(h1g, gc, bec);
    k_logits<<<(N * NC + 255) / 256, 256, 0, stream>>>(h1g, Wc2, bc2, out);
}

// Round 10
// 1232.261 us; speedup vs baseline: 9.2598x; 1.5187x over previous
//
#include <hip/hip_runtime.h>
#include <math.h>

#define T 8
#define N 5000
#define E 160000
#define EN (E + N)
#define IN_DIM 64
#define HID 128
#define H 8
#define D 16
#define NC 2

__device__ __forceinline__ float leaky(float e) { return (e >= 0.0f) ? e : 0.2f * e; }

// h = relu(x @ W_proj + b_proj)  (all t)
__global__ void k_proj(const float* __restrict__ x, const float* __restrict__ Wp,
                       const float* __restrict__ bp, float* __restrict__ h) {
    int idx = blockIdx.x * 256 + threadIdx.x;      // < T*N*HID exact
    int c = idx & (HID - 1);
    int r = idx >> 7;
    const float* xr = x + (size_t)r * IN_DIM;
    float acc = bp[c];
    for (int k = 0; k < IN_DIM; ++k)
        acc += xr[k] * Wp[k * HID + c];
    h[idx] = fmaxf(acc, 0.0f);
}

// xh = h @ W_gat  (all t)
__global__ void k_gat(const float* __restrict__ h, const float* __restrict__ Wg,
                      float* __restrict__ xh) {
    int idx = blockIdx.x * 256 + threadIdx.x;      // < T*N*HID exact
    int c = idx & (HID - 1);
    int r = idx >> 7;
    const float* hr = h + (size_t)r * HID;
    float acc = 0.0f;
    for (int k = 0; k < HID; ++k)
        acc += hr[k] * Wg[k * HID + c];
    xh[idx] = acc;
}

// a_s/a_d  (all t)
__global__ void k_coef(const float* __restrict__ xh, const float* __restrict__ asrc,
                       const float* __restrict__ adst, float* __restrict__ a_s,
                       float* __restrict__ a_d) {
    int idx = blockIdx.x * 256 + threadIdx.x;
    if (idx >= T * N * H) return;
    int hh = idx & (H - 1);
    int r  = idx >> 3;
    const float* row = xh + (size_t)r * HID + hh * D;
    float s1 = 0.0f, s2 = 0.0f;
    for (int d = 0; d < D; ++d) {
        s1 += row[d] * asrc[hh * D + d];
        s2 += row[d] * adst[hh * D + d];
    }
    a_s[idx] = s1;
    a_d[idx] = s2;
}

__device__ __forceinline__ void esd_g(const int* __restrict__ ei, int t, int i,
                                      int& s, int& d) {
    if (i < E) {
        s = ei[(size_t)(2 * t) * E + i];
        d = ei[(size_t)(2 * t + 1) * E + i];
    } else {
        s = d = i - E;
    }
}

__global__ void k_hist(const int* __restrict__ ei, int* __restrict__ cursor) {
    int idx = blockIdx.x * 256 + threadIdx.x;
    if (idx >= T * EN) return;
    int t = idx / EN;
    int i = idx - t * EN;
    int s, d;
    esd_g(ei, t, i, s, d);
    atomicAdd(&cursor[t * N + d], 1);
}

__global__ void k_scan(int* __restrict__ cursor, int* __restrict__ offs) {
    __shared__ int part[256];
    int t = blockIdx.x;
    int tid = threadIdx.x;
    const int CH = 20;
    int begin = tid * CH;
    int sum = 0;
    for (int k = 0; k < CH; ++k) {
        int i = begin + k;
        if (i < N) sum += cursor[t * N + i];
    }
    part[tid] = sum;
    __syncthreads();
    if (tid == 0) {
        int run = 0;
        for (int i = 0; i < 256; ++i) { int v = part[i]; part[i] = run; run += v; }
        offs[t * (N + 1) + N] = run;
    }
    __syncthreads();
    int run = part[tid];
    for (int k = 0; k < CH; ++k) {
        int i = begin + k;
        if (i < N) {
            int cnt = cursor[t * N + i];
            offs[t * (N + 1) + i] = run;
            cursor[t * N + i] = run;
            run += cnt;
        }
    }
}

__global__ void k_scatter(const int* __restrict__ ei, int* __restrict__ cursor,
                          int* __restrict__ csr_src) {
    int idx = blockIdx.x * 256 + threadIdx.x;
    if (idx >= T * EN) return;
    int t = idx / EN;
    int i = idx - t * EN;
    int s, d;
    esd_g(ei, t, i, s, d);
    int pos = atomicAdd(&cursor[t * N + d], 1);
    csr_src[(size_t)t * EN + pos] = s;
}

// GAT softmax + aggregation, one block per (t,dst), atomic-free
__global__ __launch_bounds__(128) void k_aggc(
        const int* __restrict__ offs, const int* __restrict__ csr_src,
        const float* __restrict__ a_s, const float* __restrict__ a_d,
        const float* __restrict__ xh, float* __restrict__ gout) {
    int b = blockIdx.x;                  // t*N + dst
    int t = b / N;
    int dst = b - t * N;
    int tid = threadIdx.x;

    int o0 = offs[t * (N + 1) + dst];
    int o1 = offs[t * (N + 1) + dst + 1];
    int deg = o1 - o0;
    const int* esrc = csr_src + (size_t)t * EN + o0;
    const float* as_b = a_s + (size_t)t * N * H;
    const float* ad_b = a_d + (size_t)t * N * H;
    const float* xh_b = xh + (size_t)t * N * HID;

    __shared__ float lm[H][16], ls[H][16];
    __shared__ float fm[H], finv[H];
    __shared__ float lal[16][H];
    __shared__ int   lsrc[16];

    {
        int ha = tid & 7, l = tid >> 3;
        float ad_h = ad_b[dst * H + ha];
        float m = -1e30f, ssum = 0.0f;
        for (int i = l; i < deg; i += 16) {
            int src = esrc[i];
            float e = leaky(as_b[src * H + ha] + ad_h);
            if (e > m) { ssum = ssum * expf(m - e) + 1.0f; m = e; }
            else       { ssum += expf(e - m); }
        }
        lm[ha][l] = m;
        ls[ha][l] = ssum;
    }
    __syncthreads();
    if (tid < H) {
        float mm = -1e30f;
        for (int l = 0; l < 16; ++l) mm = fmaxf(mm, lm[tid][l]);
        float ss = 0.0f;
        for (int l = 0; l < 16; ++l) ss += ls[tid][l] * expf(lm[tid][l] - mm);
        fm[tid] = mm;
        finv[tid] = 1.0f / (ss + 1e-16f);
    }
    __syncthreads();

    int h = tid >> 4;
    int eh_e = tid >> 3, eh_h = tid & 7;
    float acc = 0.0f;
    for (int base = 0; base < deg; base += 16) {
        int ej = base + eh_e;
        if (ej < deg) {
            int src = esrc[ej];
            if (eh_h == 0) lsrc[eh_e] = src;
            float e = leaky(as_b[src * H + eh_h] + ad_b[dst * H + eh_h]);
            lal[eh_e][eh_h] = expf(e - fm[eh_h]) * finv[eh_h];
        }
        __syncthreads();
        int lim = min(16, deg - base);
        for (int j = 0; j < lim; ++j)
            acc += lal[j][h] * xh_b[(size_t)lsrc[j] * HID + tid];
        __syncthreads();
    }
    gout[(size_t)b * HID + tid] = acc;
}

// fused per-node: LN1 -> k/v (all t) + q(T-1) -> attention -> W_o -> LN2
// -> emb(+div+noise) -> out ; classifier: Wc1 -> LN3 -> gelu -> Wc2 -> out
__global__ __launch_bounds__(128) void k_node(
        const float* __restrict__ gout, const float* __restrict__ b_gat,
        const float* __restrict__ g1, const float* __restrict__ be1,
        const float* __restrict__ W_qkv, const float* __restrict__ b_qkv,
        const float* __restrict__ W_o, const float* __restrict__ b_o,
        const float* __restrict__ g2, const float* __restrict__ be2,
        const float* __restrict__ noise,
        const float* __restrict__ Wc1, const float* __restrict__ bc1,
        const float* __restrict__ gc, const float* __restrict__ bec,
        const float* __restrict__ Wc2, const float* __restrict__ bc2,
        float* __restrict__ out) {
    __shared__ float nf[T][HID];
    __shared__ float nrm[T][HID];
    __shared__ float ql[HID];
    __shared__ float kl[H][T][D];
    __shared__ float vl[H][T][D];
    __shared__ float attn_l[H][T];
    __shared__ float ta[HID];
    __shared__ float red[128];
    __shared__ float emb_l[HID];
    __shared__ float h1_l[HID];
    __shared__ float mu1[T], rs1[T];

    int n = blockIdx.x;
    int tid = threadIdx.x;

    // load nf (t-major gout)
    for (int idx = tid; idx < T * HID; idx += 128) {
        int t = idx >> 7, c = idx & 127;
        nf[t][c] = gout[(size_t)(t * N + n) * HID + c] + b_gat[c];
    }
    __syncthreads();

    // LN1 stats (validated serial form)
    if (tid < T) {
        float p = 0.0f;
        for (int c = 0; c < HID; ++c) p += nf[tid][c];
        float mu = p * (1.0f / HID);
        float v = 0.0f;
        for (int c = 0; c < HID; ++c) { float dd = nf[tid][c] - mu; v += dd * dd; }
        mu1[tid] = mu;
        rs1[tid] = rsqrtf(v * (1.0f / HID) + 1e-5f);
    }
    __syncthreads();
    for (int idx = tid; idx < T * HID; idx += 128) {
        int t = idx >> 7, c = idx & 127;
        nrm[t][c] = (nf[t][c] - mu1[t]) * rs1[t] * g1[c] + be1[c];
    }
    __syncthreads();

    // k/v for all t (2*T*HID outputs), q for t=T-1 (HID outputs)
    for (int idx = tid; idx < T * 2 * HID; idx += 128) {
        int tt = idx / (2 * HID);
        int rem = idx - tt * 2 * HID;
        int which = rem >> 7;            // 0 = k, 1 = v
        int f = rem & 127;
        int j = (1 + which) * HID + f;   // W_qkv row
        float acc = b_qkv[j];
        const float* w = W_qkv + (size_t)j * HID;
        for (int c = 0; c < HID; ++c) acc += nrm[tt][c] * w[c];
        int hh = f >> 4, dd = f & 15;
        if (which == 0) kl[hh][tt][dd] = acc;
        else            vl[hh][tt][dd] = acc;
    }
    {
        int j = tid;                     // q row
        float acc = b_qkv[j];
        const float* w = W_qkv + (size_t)j * HID;
        for (int c = 0; c < HID; ++c) acc += nrm[T - 1][c] * w[c];
        ql[tid] = acc;
    }
    __syncthreads();

    // attention scores for query t=T-1
    if (tid < H) {
        int hh = tid;
        float sc[T];
        float mx = -1e30f;
        for (int tk = 0; tk < T; ++tk) {
            float a = 0.0f;
            for (int dd = 0; dd < D; ++dd) a += ql[hh * D + dd] * kl[hh][tk][dd];
            a *= 0.25f;                  // 1/sqrt(16)
            sc[tk] = a;
            mx = fmaxf(mx, a);
        }
        float ssum = 0.0f;
        for (int tk = 0; tk < T; ++tk) { sc[tk] = expf(sc[tk] - mx); ssum += sc[tk]; }
        float inv = 1.0f / ssum;
        for (int tk = 0; tk < T; ++tk) attn_l[hh][tk] = sc[tk] * inv;
    }
    __syncthreads();

    {
        int c = tid, hh = c >> 4, dd = c & 15;
        float a = 0.0f;
        for (int tk = 0; tk < T; ++tk) a += attn_l[hh][tk] * vl[hh][tk][dd];
        ta[c] = a;
    }
    __syncthreads();

    // W_o + residual
    float o = b_o[tid];
    {
        const float* w = W_o + (size_t)tid * HID;
        for (int k = 0; k < HID; ++k) o += ta[k] * w[k];
    }
    float x2 = nf[T - 1][tid] + o;

    // LN2 (block tree reduce)
    red[tid] = x2; __syncthreads();
    for (int st = 64; st > 0; st >>= 1) { if (tid < st) red[tid] += red[tid + st]; __syncthreads(); }
    float mu2 = red[0] * (1.0f / HID); __syncthreads();
    float d2 = x2 - mu2;
    red[tid] = d2 * d2; __syncthreads();
    for (int st = 64; st > 0; st >>= 1) { if (tid < st) red[tid] += red[tid + st]; __syncthreads(); }
    float rstd2 = rsqrtf(red[0] * (1.0f / HID) + 1e-5f); __syncthreads();

    float div = sinf(((float)n / (float)N) * 6.28f) * 0.1f;
    float emb = d2 * rstd2 * g2[tid] + be2[tid]
              + div + noise[(size_t)n * HID + tid] * 0.05f;
    emb_l[tid] = emb;
    out[(size_t)n * HID + tid] = emb;
    __syncthreads();

    // classifier
    float h1 = bc1[tid];
    for (int c = 0; c < HID; ++c) h1 += emb_l[c] * Wc1[c * HID + tid];

    red[tid] = h1; __syncthreads();
    for (int st = 64; st > 0; st >>= 1) { if (tid < st) red[tid] += red[tid + st]; __syncthreads(); }
    float mu3 = red[0] * (1.0f / HID); __syncthreads();
    float d3 = h1 - mu3;
    red[tid] = d3 * d3; __syncthreads();
    for (int st = 64; st > 0; st >>= 1) { if (tid < st) red[tid] += red[tid + st]; __syncthreads(); }
    float rstd3 = rsqrtf(red[0] * (1.0f / HID) + 1e-5f); __syncthreads();

    float lnv = d3 * rstd3 * gc[tid] + bec[tid];
    h1_l[tid] = 0.5f * lnv * (1.0f + erff(lnv * 0.70710678118f));
    __syncthreads();

    if (tid < NC) {
        float acc = bc2[tid];
        for (int c = 0; c < HID; ++c) acc += h1_l[c] * Wc2[c * NC + tid];
        if (tid == 1) acc += sinf((float)n * 0.5f) * 0.2f;
        out[(size_t)N * HID + (size_t)n * NC + tid] = acc;
    }
}

extern "C" void kernel_launch(void* const* d_in, const int* in_sizes, int n_in,
                              void* d_out, int out_size, void* d_ws, size_t ws_size,
                              hipStream_t stream) {
    const float* x      = (const float*)d_in[0];
    const int*   ei     = (const int*)d_in[1];
    const float* noise  = (const float*)d_in[2];
    const float* W_proj = (const float*)d_in[3];
    const float* b_proj = (const float*)d_in[4];
    const float* W_gat  = (const float*)d_in[5];
    const float* a_src  = (const float*)d_in[6];
    const float* a_dst  = (const float*)d_in[7];
    const float* b_gat  = (const float*)d_in[8];
    const float* g1     = (const float*)d_in[9];
    const float* be1    = (const float*)d_in[10];
    const float* W_qkv  = (const float*)d_in[11];
    const float* b_qkv  = (const float*)d_in[12];
    const float* W_o    = (const float*)d_in[13];
    const float* b_o    = (const float*)d_in[14];
    const float* g2     = (const float*)d_in[15];
    const float* be2    = (const float*)d_in[16];
    const float* Wc1    = (const float*)d_in[17];
    const float* bc1    = (const float*)d_in[18];
    const float* gc     = (const float*)d_in[19];
    const float* bec    = (const float*)d_in[20];
    const float* Wc2    = (const float*)d_in[21];
    const float* bc2    = (const float*)d_in[22];
    float* out = (float*)d_out;

    float* xh    = (float*)d_ws;                 // 5,120,000
    float* gout  = xh + 5120000;                 // 5,120,000 (h alias pre-agg)
    float* a_s   = gout + 5120000;               //   320,000
    float* a_d   = a_s + 320000;                 //   320,000
    int*   offs    = (int*)(a_d + 320000);       //    40,008
    int*   cursor  = offs + 40008;               //    40,000
    int*   csr_src = cursor + 40000;             // 1,320,000

    float* h = gout;                             // alias

    k_proj<<<T * N * HID / 256, 256, 0, stream>>>(x, W_proj, b_proj, h);
    k_gat<<<T * N * HID / 256, 256, 0, stream>>>(h, W_gat, xh);
    k_coef<<<(T * N * H + 255) / 256, 256, 0, stream>>>(xh, a_src, a_dst, a_s, a_d);

    hipMemsetAsync(cursor, 0, 40000 * sizeof(int), stream);
    k_hist<<<(T * EN + 255) / 256, 256, 0, stream>>>(ei, cursor);
    k_scan<<<T, 256, 0, stream>>>(cursor, offs);
    k_scatter<<<(T * EN + 255) / 256, 256, 0, stream>>>(ei, cursor, csr_src);

    k_aggc<<<T * N, 128, 0, stream>>>(offs, csr_src, a_s, a_d, xh, gout);

    k_node<<<N, 128, 0, stream>>>(gout, b_gat, g1, be1, W_qkv, b_qkv, W_o, b_o,
                                  g2, be2, noise, Wc1, bc1, gc, bec, Wc2, bc2, out);
}

// Round 11
// 668.550 us; speedup vs baseline: 17.0676x; 1.8432x over previous
//
#include <hip/hip_runtime.h>
#include <math.h>

#define T 8
#define N 5000
#define E 160000
#define EN (E + N)
#define IN_DIM 64
#define HID 128
#define H 8
#define D 16
#define NC 2

__device__ __forceinline__ float leaky(float e) { return (e >= 0.0f) ? e : 0.2f * e; }

// h = relu(x @ W_proj + b_proj)  (all t)
__global__ void k_proj(const float* __restrict__ x, const float* __restrict__ Wp,
                       const float* __restrict__ bp, float* __restrict__ h) {
    int idx = blockIdx.x * 256 + threadIdx.x;      // < T*N*HID exact
    int c = idx & (HID - 1);
    int r = idx >> 7;
    const float* xr = x + (size_t)r * IN_DIM;
    float acc = bp[c];
    for (int k = 0; k < IN_DIM; ++k)
        acc += xr[k] * Wp[k * HID + c];
    h[idx] = fmaxf(acc, 0.0f);
}

// xh = h @ W_gat  (all t)
__global__ void k_gat(const float* __restrict__ h, const float* __restrict__ Wg,
                      float* __restrict__ xh) {
    int idx = blockIdx.x * 256 + threadIdx.x;      // < T*N*HID exact
    int c = idx & (HID - 1);
    int r = idx >> 7;
    const float* hr = h + (size_t)r * HID;
    float acc = 0.0f;
    for (int k = 0; k < HID; ++k)
        acc += hr[k] * Wg[k * HID + c];
    xh[idx] = acc;
}

// a_s/a_d  (all t)
__global__ void k_coef(const float* __restrict__ xh, const float* __restrict__ asrc,
                       const float* __restrict__ adst, float* __restrict__ a_s,
                       float* __restrict__ a_d) {
    int idx = blockIdx.x * 256 + threadIdx.x;
    if (idx >= T * N * H) return;
    int hh = idx & (H - 1);
    int r  = idx >> 3;
    const float* row = xh + (size_t)r * HID + hh * D;
    float s1 = 0.0f, s2 = 0.0f;
    for (int d = 0; d < D; ++d) {
        s1 += row[d] * asrc[hh * D + d];
        s2 += row[d] * adst[hh * D + d];
    }
    a_s[idx] = s1;
    a_d[idx] = s2;
}

// transpose W_qkv (384x128 -> 128x384) and W_o (128x128 -> 128x128)
__global__ void k_tr(const float* __restrict__ W_qkv, const float* __restrict__ W_o,
                     float* __restrict__ WTq, float* __restrict__ WoT) {
    int idx = blockIdx.x * 256 + threadIdx.x;
    if (idx < 384 * 128) {
        int j = idx >> 7, c = idx & 127;
        WTq[c * 384 + j] = W_qkv[idx];
    } else if (idx < 384 * 128 + 128 * 128) {
        int r = idx - 384 * 128;
        int j = r >> 7, k = r & 127;
        WoT[k * 128 + j] = W_o[r];
    }
}

__device__ __forceinline__ void esd_g(const int* __restrict__ ei, int t, int i,
                                      int& s, int& d) {
    if (i < E) {
        s = ei[(size_t)(2 * t) * E + i];
        d = ei[(size_t)(2 * t + 1) * E + i];
    } else {
        s = d = i - E;
    }
}

__global__ void k_hist(const int* __restrict__ ei, int* __restrict__ cursor) {
    int idx = blockIdx.x * 256 + threadIdx.x;
    if (idx >= T * EN) return;
    int t = idx / EN;
    int i = idx - t * EN;
    int s, d;
    esd_g(ei, t, i, s, d);
    atomicAdd(&cursor[t * N + d], 1);
}

__global__ void k_scan(int* __restrict__ cursor, int* __restrict__ offs) {
    __shared__ int part[256];
    int t = blockIdx.x;
    int tid = threadIdx.x;
    const int CH = 20;
    int begin = tid * CH;
    int sum = 0;
    for (int k = 0; k < CH; ++k) {
        int i = begin + k;
        if (i < N) sum += cursor[t * N + i];
    }
    part[tid] = sum;
    __syncthreads();
    if (tid == 0) {
        int run = 0;
        for (int i = 0; i < 256; ++i) { int v = part[i]; part[i] = run; run += v; }
        offs[t * (N + 1) + N] = run;
    }
    __syncthreads();
    int run = part[tid];
    for (int k = 0; k < CH; ++k) {
        int i = begin + k;
        if (i < N) {
            int cnt = cursor[t * N + i];
            offs[t * (N + 1) + i] = run;
            cursor[t * N + i] = run;
            run += cnt;
        }
    }
}

__global__ void k_scatter(const int* __restrict__ ei, int* __restrict__ cursor,
                          int* __restrict__ csr_src) {
    int idx = blockIdx.x * 256 + threadIdx.x;
    if (idx >= T * EN) return;
    int t = idx / EN;
    int i = idx - t * EN;
    int s, d;
    esd_g(ei, t, i, s, d);
    int pos = atomicAdd(&cursor[t * N + d], 1);
    csr_src[(size_t)t * EN + pos] = s;
}

// GAT softmax + aggregation, one block per (t,dst), atomic-free
__global__ __launch_bounds__(128) void k_aggc(
        const int* __restrict__ offs, const int* __restrict__ csr_src,
        const float* __restrict__ a_s, const float* __restrict__ a_d,
        const float* __restrict__ xh, float* __restrict__ gout) {
    int b = blockIdx.x;                  // t*N + dst
    int t = b / N;
    int dst = b - t * N;
    int tid = threadIdx.x;

    int o0 = offs[t * (N + 1) + dst];
    int o1 = offs[t * (N + 1) + dst + 1];
    int deg = o1 - o0;
    const int* esrc = csr_src + (size_t)t * EN + o0;
    const float* as_b = a_s + (size_t)t * N * H;
    const float* ad_b = a_d + (size_t)t * N * H;
    const float* xh_b = xh + (size_t)t * N * HID;

    __shared__ float lm[H][16], ls[H][16];
    __shared__ float fm[H], finv[H];
    __shared__ float lal[16][H];
    __shared__ int   lsrc[16];

    {
        int ha = tid & 7, l = tid >> 3;
        float ad_h = ad_b[dst * H + ha];
        float m = -1e30f, ssum = 0.0f;
        for (int i = l; i < deg; i += 16) {
            int src = esrc[i];
            float e = leaky(as_b[src * H + ha] + ad_h);
            if (e > m) { ssum = ssum * expf(m - e) + 1.0f; m = e; }
            else       { ssum += expf(e - m); }
        }
        lm[ha][l] = m;
        ls[ha][l] = ssum;
    }
    __syncthreads();
    if (tid < H) {
        float mm = -1e30f;
        for (int l = 0; l < 16; ++l) mm = fmaxf(mm, lm[tid][l]);
        float ss = 0.0f;
        for (int l = 0; l < 16; ++l) ss += ls[tid][l] * expf(lm[tid][l] - mm);
        fm[tid] = mm;
        finv[tid] = 1.0f / (ss + 1e-16f);
    }
    __syncthreads();

    int h = tid >> 4;
    int eh_e = tid >> 3, eh_h = tid & 7;
    float acc = 0.0f;
    for (int base = 0; base < deg; base += 16) {
        int ej = base + eh_e;
        if (ej < deg) {
            int src = esrc[ej];
            if (eh_h == 0) lsrc[eh_e] = src;
            float e = leaky(as_b[src * H + eh_h] + ad_b[dst * H + eh_h]);
            lal[eh_e][eh_h] = expf(e - fm[eh_h]) * finv[eh_h];
        }
        __syncthreads();
        int lim = min(16, deg - base);
        for (int j = 0; j < lim; ++j)
            acc += lal[j][h] * xh_b[(size_t)lsrc[j] * HID + tid];
        __syncthreads();
    }
    gout[(size_t)b * HID + tid] = acc;
}

// fused per-node pipeline, coalesced transposed-weight access
__global__ __launch_bounds__(128) void k_node(
        const float* __restrict__ gout, const float* __restrict__ b_gat,
        const float* __restrict__ g1, const float* __restrict__ be1,
        const float* __restrict__ WTq, const float* __restrict__ b_qkv,
        const float* __restrict__ WoT, const float* __restrict__ b_o,
        const float* __restrict__ g2, const float* __restrict__ be2,
        const float* __restrict__ noise,
        const float* __restrict__ Wc1, const float* __restrict__ bc1,
        const float* __restrict__ gc, const float* __restrict__ bec,
        const float* __restrict__ Wc2, const float* __restrict__ bc2,
        float* __restrict__ out) {
    __shared__ float nf[T][HID];
    __shared__ float nrm[T][HID];
    __shared__ float ql[HID];
    __shared__ float kl[H][T][D];
    __shared__ float vl[H][T][D];
    __shared__ float attn_l[H][T];
    __shared__ float ta[HID];
    __shared__ float red[128];
    __shared__ float emb_l[HID];
    __shared__ float h1_l[HID];
    __shared__ float mu1[T], rs1[T];

    int n = blockIdx.x;
    int tid = threadIdx.x;

    for (int idx = tid; idx < T * HID; idx += 128) {
        int t = idx >> 7, c = idx & 127;
        nf[t][c] = gout[(size_t)(t * N + n) * HID + c] + b_gat[c];
    }
    __syncthreads();

    if (tid < T) {
        float p = 0.0f;
        for (int c = 0; c < HID; ++c) p += nf[tid][c];
        float mu = p * (1.0f / HID);
        float v = 0.0f;
        for (int c = 0; c < HID; ++c) { float dd = nf[tid][c] - mu; v += dd * dd; }
        mu1[tid] = mu;
        rs1[tid] = rsqrtf(v * (1.0f / HID) + 1e-5f);
    }
    __syncthreads();
    for (int idx = tid; idx < T * HID; idx += 128) {
        int t = idx >> 7, c = idx & 127;
        nrm[t][c] = (nf[t][c] - mu1[t]) * rs1[t] * g1[c] + be1[c];
    }
    __syncthreads();

    // k and v: thread = output column, t-batched accumulators, coalesced WTq
    {
        int hh = tid >> 4, dd = tid & 15;
        for (int which = 0; which < 2; ++which) {
            int j = (1 + which) * HID + tid;        // W_qkv row index
            float b = b_qkv[j];
            float acc[T];
            #pragma unroll
            for (int tt = 0; tt < T; ++tt) acc[tt] = b;
            for (int c = 0; c < HID; c += 4) {
                float w0 = WTq[(size_t)(c + 0) * 384 + j];
                float w1 = WTq[(size_t)(c + 1) * 384 + j];
                float w2 = WTq[(size_t)(c + 2) * 384 + j];
                float w3 = WTq[(size_t)(c + 3) * 384 + j];
                #pragma unroll
                for (int tt = 0; tt < T; ++tt) {
                    acc[tt] += nrm[tt][c] * w0 + nrm[tt][c + 1] * w1
                             + nrm[tt][c + 2] * w2 + nrm[tt][c + 3] * w3;
                }
            }
            #pragma unroll
            for (int tt = 0; tt < T; ++tt) {
                if (which == 0) kl[hh][tt][dd] = acc[tt];
                else            vl[hh][tt][dd] = acc[tt];
            }
        }
    }
    // q at t = T-1
    {
        int j = tid;
        float acc = b_qkv[j];
        for (int c = 0; c < HID; ++c) acc += nrm[T - 1][c] * WTq[(size_t)c * 384 + j];
        ql[tid] = acc;
    }
    __syncthreads();

    if (tid < H) {
        int hh = tid;
        float sc[T];
        float mx = -1e30f;
        for (int tk = 0; tk < T; ++tk) {
            float a = 0.0f;
            for (int dd = 0; dd < D; ++dd) a += ql[hh * D + dd] * kl[hh][tk][dd];
            a *= 0.25f;
            sc[tk] = a;
            mx = fmaxf(mx, a);
        }
        float ssum = 0.0f;
        for (int tk = 0; tk < T; ++tk) { sc[tk] = expf(sc[tk] - mx); ssum += sc[tk]; }
        float inv = 1.0f / ssum;
        for (int tk = 0; tk < T; ++tk) attn_l[hh][tk] = sc[tk] * inv;
    }
    __syncthreads();

    {
        int c = tid, hh = c >> 4, dd = c & 15;
        float a = 0.0f;
        for (int tk = 0; tk < T; ++tk) a += attn_l[hh][tk] * vl[hh][tk][dd];
        ta[c] = a;
    }
    __syncthreads();

    // W_o (transposed, coalesced) + residual
    float o = b_o[tid];
    for (int k = 0; k < HID; ++k) o += ta[k] * WoT[(size_t)k * 128 + tid];
    float x2 = nf[T - 1][tid] + o;

    red[tid] = x2; __syncthreads();
    for (int st = 64; st > 0; st >>= 1) { if (tid < st) red[tid] += red[tid + st]; __syncthreads(); }
    float mu2 = red[0] * (1.0f / HID); __syncthreads();
    float d2 = x2 - mu2;
    red[tid] = d2 * d2; __syncthreads();
    for (int st = 64; st > 0; st >>= 1) { if (tid < st) red[tid] += red[tid + st]; __syncthreads(); }
    float rstd2 = rsqrtf(red[0] * (1.0f / HID) + 1e-5f); __syncthreads();

    float div = sinf(((float)n / (float)N) * 6.28f) * 0.1f;
    float emb = d2 * rstd2 * g2[tid] + be2[tid]
              + div + noise[(size_t)n * HID + tid] * 0.05f;
    emb_l[tid] = emb;
    out[(size_t)n * HID + tid] = emb;
    __syncthreads();

    float h1 = bc1[tid];
    for (int c = 0; c < HID; ++c) h1 += emb_l[c] * Wc1[c * HID + tid];   // coalesced

    red[tid] = h1; __syncthreads();
    for (int st = 64; st > 0; st >>= 1) { if (tid < st) red[tid] += red[tid + st]; __syncthreads(); }
    float mu3 = red[0] * (1.0f / HID); __syncthreads();
    float d3 = h1 - mu3;
    red[tid] = d3 * d3; __syncthreads();
    for (int st = 64; st > 0; st >>= 1) { if (tid < st) red[tid] += red[tid + st]; __syncthreads(); }
    float rstd3 = rsqrtf(red[0] * (1.0f / HID) + 1e-5f); __syncthreads();

    float lnv = d3 * rstd3 * gc[tid] + bec[tid];
    h1_l[tid] = 0.5f * lnv * (1.0f + erff(lnv * 0.70710678118f));
    __syncthreads();

    if (tid < NC) {
        float acc = bc2[tid];
        for (int c = 0; c < HID; ++c) acc += h1_l[c] * Wc2[c * NC + tid];
        if (tid == 1) acc += sinf((float)n * 0.5f) * 0.2f;
        out[(size_t)N * HID + (size_t)n * NC + tid] = acc;
    }
}

extern "C" void kernel_launch(void* const* d_in, const int* in_sizes, int n_in,
                              void* d_out, int out_size, void* d_ws, size_t ws_size,
                              hipStream_t stream) {
    const float* x      = (const float*)d_in[0];
    const int*   ei     = (const int*)d_in[1];
    const float* noise  = (const float*)d_in[2];
    const float* W_proj = (const float*)d_in[3];
    const float* b_proj = (const float*)d_in[4];
    const float* W_gat  = (const float*)d_in[5];
    const float* a_src  = (const float*)d_in[6];
    const float* a_dst  = (const float*)d_in[7];
    const float* b_gat  = (const float*)d_in[8];
    const float* g1     = (const float*)d_in[9];
    const float* be1    = (const float*)d_in[10];
    const float* W_qkv  = (const float*)d_in[11];
    const float* b_qkv  = (const float*)d_in[12];
    const float* W_o    = (const float*)d_in[13];
    const float* b_o    = (const float*)d_in[14];
    const float* g2     = (const float*)d_in[15];
    const float* be2    = (const float*)d_in[16];
    const float* Wc1    = (const float*)d_in[17];
    const float* bc1    = (const float*)d_in[18];
    const float* gc     = (const float*)d_in[19];
    const float* bec    = (const float*)d_in[20];
    const float* Wc2    = (const float*)d_in[21];
    const float* bc2    = (const float*)d_in[22];
    float* out = (float*)d_out;

    float* xh    = (float*)d_ws;                 // 5,120,000
    float* gout  = xh + 5120000;                 // 5,120,000 (h alias pre-agg)
    float* a_s   = gout + 5120000;               //   320,000
    float* a_d   = a_s + 320000;                 //   320,000
    int*   offs    = (int*)(a_d + 320000);       //    40,008
    int*   cursor  = offs + 40008;               //    40,000
    int*   csr_src = cursor + 40000;             // 1,320,000
    float* WTq   = (float*)(csr_src + 1320000);  //    49,152
    float* WoT   = WTq + 49152;                  //    16,384

    float* h = gout;                             // alias

    k_tr<<<(384 * 128 + 128 * 128 + 255) / 256, 256, 0, stream>>>(W_qkv, W_o, WTq, WoT);

    k_proj<<<T * N * HID / 256, 256, 0, stream>>>(x, W_proj, b_proj, h);
    k_gat<<<T * N * HID / 256, 256, 0, stream>>>(h, W_gat, xh);
    k_coef<<<(T * N * H + 255) / 256, 256, 0, stream>>>(xh, a_src, a_dst, a_s, a_d);

    hipMemsetAsync(cursor, 0, 40000 * sizeof(int), stream);
    k_hist<<<(T * EN + 255) / 256, 256, 0, stream>>>(ei, cursor);
    k_scan<<<T, 256, 0, stream>>>(cursor, offs);
    k_scatter<<<(T * EN + 255) / 256, 256, 0, stream>>>(ei, cursor, csr_src);

    k_aggc<<<T * N, 128, 0, stream>>>(offs, csr_src, a_s, a_d, xh, gout);

    k_node<<<N, 128, 0, stream>>>(gout, b_gat, g1, be1, WTq, b_qkv, WoT, b_o,
                                  g2, be2, noise, Wc1, bc1, gc, bec, Wc2, bc2, out);
}

// Round 12
// 486.545 us; speedup vs baseline: 23.4522x; 1.3741x over previous
//
#include <hip/hip_runtime.h>
#include <math.h>

#define T 8
#define N 5000
#define E 160000
#define EN (E + N)
#define IN_DIM 64
#define HID 128
#define H 8
#define D 16
#define NC 2
#define MT 32            // rows per k_pg block

__device__ __forceinline__ float leaky(float e) { return (e >= 0.0f) ? e : 0.2f * e; }

// fused h=relu(x@Wp+bp); xh=h@Wg — 32-row tile, 4x4 register blocking
__global__ __launch_bounds__(256) void k_pg(const float* __restrict__ x,
                                            const float* __restrict__ Wp,
                                            const float* __restrict__ bp,
                                            const float* __restrict__ Wg,
                                            float* __restrict__ xh) {
    __shared__ float xt[MT][IN_DIM];   // 8 KB
    __shared__ float ht[MT][HID];      // 16 KB
    int row0 = blockIdx.x * MT;
    int tid = threadIdx.x;

    for (int idx = tid; idx < MT * IN_DIM; idx += 256) {
        int r = idx >> 6, k = idx & 63;
        xt[r][k] = x[(size_t)(row0 + r) * IN_DIM + k];
    }
    __syncthreads();

    int cg = tid & 31;        // cols 4cg..4cg+3
    int rg = tid >> 5;        // rows 4rg..4rg+3
    int c0 = cg * 4, r0 = rg * 4;

    // stage B: h tile
    {
        float4 b4 = *(const float4*)(bp + c0);
        float a00=b4.x,a01=b4.y,a02=b4.z,a03=b4.w;
        float a10=b4.x,a11=b4.y,a12=b4.z,a13=b4.w;
        float a20=b4.x,a21=b4.y,a22=b4.z,a23=b4.w;
        float a30=b4.x,a31=b4.y,a32=b4.z,a33=b4.w;
        for (int k = 0; k < IN_DIM; ++k) {
            float4 w = *(const float4*)(Wp + (size_t)k * HID + c0);
            float x0 = xt[r0 + 0][k], x1 = xt[r0 + 1][k];
            float x2 = xt[r0 + 2][k], x3 = xt[r0 + 3][k];
            a00 += x0*w.x; a01 += x0*w.y; a02 += x0*w.z; a03 += x0*w.w;
            a10 += x1*w.x; a11 += x1*w.y; a12 += x1*w.z; a13 += x1*w.w;
            a20 += x2*w.x; a21 += x2*w.y; a22 += x2*w.z; a23 += x2*w.w;
            a30 += x3*w.x; a31 += x3*w.y; a32 += x3*w.z; a33 += x3*w.w;
        }
        ht[r0+0][c0+0]=fmaxf(a00,0.f); ht[r0+0][c0+1]=fmaxf(a01,0.f);
        ht[r0+0][c0+2]=fmaxf(a02,0.f); ht[r0+0][c0+3]=fmaxf(a03,0.f);
        ht[r0+1][c0+0]=fmaxf(a10,0.f); ht[r0+1][c0+1]=fmaxf(a11,0.f);
        ht[r0+1][c0+2]=fmaxf(a12,0.f); ht[r0+1][c0+3]=fmaxf(a13,0.f);
        ht[r0+2][c0+0]=fmaxf(a20,0.f); ht[r0+2][c0+1]=fmaxf(a21,0.f);
        ht[r0+2][c0+2]=fmaxf(a22,0.f); ht[r0+2][c0+3]=fmaxf(a23,0.f);
        ht[r0+3][c0+0]=fmaxf(a30,0.f); ht[r0+3][c0+1]=fmaxf(a31,0.f);
        ht[r0+3][c0+2]=fmaxf(a32,0.f); ht[r0+3][c0+3]=fmaxf(a33,0.f);
    }
    __syncthreads();

    // stage C: xh tile
    {
        float a00=0,a01=0,a02=0,a03=0, a10=0,a11=0,a12=0,a13=0;
        float a20=0,a21=0,a22=0,a23=0, a30=0,a31=0,a32=0,a33=0;
        for (int k = 0; k < HID; ++k) {
            float4 w = *(const float4*)(Wg + (size_t)k * HID + c0);
            float h0 = ht[r0 + 0][k], h1 = ht[r0 + 1][k];
            float h2 = ht[r0 + 2][k], h3 = ht[r0 + 3][k];
            a00 += h0*w.x; a01 += h0*w.y; a02 += h0*w.z; a03 += h0*w.w;
            a10 += h1*w.x; a11 += h1*w.y; a12 += h1*w.z; a13 += h1*w.w;
            a20 += h2*w.x; a21 += h2*w.y; a22 += h2*w.z; a23 += h2*w.w;
            a30 += h3*w.x; a31 += h3*w.y; a32 += h3*w.z; a33 += h3*w.w;
        }
        float4 v;
        v.x=a00; v.y=a01; v.z=a02; v.w=a03;
        *(float4*)(xh + (size_t)(row0 + r0 + 0) * HID + c0) = v;
        v.x=a10; v.y=a11; v.z=a12; v.w=a13;
        *(float4*)(xh + (size_t)(row0 + r0 + 1) * HID + c0) = v;
        v.x=a20; v.y=a21; v.z=a22; v.w=a23;
        *(float4*)(xh + (size_t)(row0 + r0 + 2) * HID + c0) = v;
        v.x=a30; v.y=a31; v.z=a32; v.w=a33;
        *(float4*)(xh + (size_t)(row0 + r0 + 3) * HID + c0) = v;
    }
}

// a_s/a_d  (all t)
__global__ void k_coef(const float* __restrict__ xh, const float* __restrict__ asrc,
                       const float* __restrict__ adst, float* __restrict__ a_s,
                       float* __restrict__ a_d) {
    int idx = blockIdx.x * 256 + threadIdx.x;
    if (idx >= T * N * H) return;
    int hh = idx & (H - 1);
    int r  = idx >> 3;
    const float* row = xh + (size_t)r * HID + hh * D;
    float s1 = 0.0f, s2 = 0.0f;
    for (int d = 0; d < D; ++d) {
        s1 += row[d] * asrc[hh * D + d];
        s2 += row[d] * adst[hh * D + d];
    }
    a_s[idx] = s1;
    a_d[idx] = s2;
}

// transpose W_qkv (384x128 -> 128x384) and W_o (128x128 -> 128x128)
__global__ void k_tr(const float* __restrict__ W_qkv, const float* __restrict__ W_o,
                     float* __restrict__ WTq, float* __restrict__ WoT) {
    int idx = blockIdx.x * 256 + threadIdx.x;
    if (idx < 384 * 128) {
        int j = idx >> 7, c = idx & 127;
        WTq[c * 384 + j] = W_qkv[idx];
    } else if (idx < 384 * 128 + 128 * 128) {
        int r = idx - 384 * 128;
        int j = r >> 7, k = r & 127;
        WoT[k * 128 + j] = W_o[r];
    }
}

__device__ __forceinline__ void esd_g(const int* __restrict__ ei, int t, int i,
                                      int& s, int& d) {
    if (i < E) {
        s = ei[(size_t)(2 * t) * E + i];
        d = ei[(size_t)(2 * t + 1) * E + i];
    } else {
        s = d = i - E;
    }
}

__global__ void k_hist(const int* __restrict__ ei, int* __restrict__ cursor) {
    int idx = blockIdx.x * 256 + threadIdx.x;
    if (idx >= T * EN) return;
    int t = idx / EN;
    int i = idx - t * EN;
    int s, d;
    esd_g(ei, t, i, s, d);
    atomicAdd(&cursor[t * N + d], 1);
}

__global__ void k_scan(int* __restrict__ cursor, int* __restrict__ offs) {
    __shared__ int part[256];
    int t = blockIdx.x;
    int tid = threadIdx.x;
    const int CH = 20;
    int begin = tid * CH;
    int sum = 0;
    for (int k = 0; k < CH; ++k) {
        int i = begin + k;
        if (i < N) sum += cursor[t * N + i];
    }
    part[tid] = sum;
    __syncthreads();
    if (tid == 0) {
        int run = 0;
        for (int i = 0; i < 256; ++i) { int v = part[i]; part[i] = run; run += v; }
        offs[t * (N + 1) + N] = run;
    }
    __syncthreads();
    int run = part[tid];
    for (int k = 0; k < CH; ++k) {
        int i = begin + k;
        if (i < N) {
            int cnt = cursor[t * N + i];
            offs[t * (N + 1) + i] = run;
            cursor[t * N + i] = run;
            run += cnt;
        }
    }
}

__global__ void k_scatter(const int* __restrict__ ei, int* __restrict__ cursor,
                          int* __restrict__ csr_src) {
    int idx = blockIdx.x * 256 + threadIdx.x;
    if (idx >= T * EN) return;
    int t = idx / EN;
    int i = idx - t * EN;
    int s, d;
    esd_g(ei, t, i, s, d);
    int pos = atomicAdd(&cursor[t * N + d], 1);
    csr_src[(size_t)t * EN + pos] = s;
}

// GAT softmax + aggregation, one block per (t,dst), atomic-free
__global__ __launch_bounds__(128) void k_aggc(
        const int* __restrict__ offs, const int* __restrict__ csr_src,
        const float* __restrict__ a_s, const float* __restrict__ a_d,
        const float* __restrict__ xh, float* __restrict__ gout) {
    int b = blockIdx.x;                  // t*N + dst
    int t = b / N;
    int dst = b - t * N;
    int tid = threadIdx.x;

    int o0 = offs[t * (N + 1) + dst];
    int o1 = offs[t * (N + 1) + dst + 1];
    int deg = o1 - o0;
    const int* esrc = csr_src + (size_t)t * EN + o0;
    const float* as_b = a_s + (size_t)t * N * H;
    const float* ad_b = a_d + (size_t)t * N * H;
    const float* xh_b = xh + (size_t)t * N * HID;

    __shared__ float lm[H][16], ls[H][16];
    __shared__ float fm[H], finv[H];
    __shared__ float lal[16][H];
    __shared__ int   lsrc[16];

    {
        int ha = tid & 7, l = tid >> 3;
        float ad_h = ad_b[dst * H + ha];
        float m = -1e30f, ssum = 0.0f;
        for (int i = l; i < deg; i += 16) {
            int src = esrc[i];
            float e = leaky(as_b[src * H + ha] + ad_h);
            if (e > m) { ssum = ssum * expf(m - e) + 1.0f; m = e; }
            else       { ssum += expf(e - m); }
        }
        lm[ha][l] = m;
        ls[ha][l] = ssum;
    }
    __syncthreads();
    if (tid < H) {
        float mm = -1e30f;
        for (int l = 0; l < 16; ++l) mm = fmaxf(mm, lm[tid][l]);
        float ss = 0.0f;
        for (int l = 0; l < 16; ++l) ss += ls[tid][l] * expf(lm[tid][l] - mm);
        fm[tid] = mm;
        finv[tid] = 1.0f / (ss + 1e-16f);
    }
    __syncthreads();

    int h = tid >> 4;
    int eh_e = tid >> 3, eh_h = tid & 7;
    float acc = 0.0f;
    for (int base = 0; base < deg; base += 16) {
        int ej = base + eh_e;
        if (ej < deg) {
            int src = esrc[ej];
            if (eh_h == 0) lsrc[eh_e] = src;
            float e = leaky(as_b[src * H + eh_h] + ad_b[dst * H + eh_h]);
            lal[eh_e][eh_h] = expf(e - fm[eh_h]) * finv[eh_h];
        }
        __syncthreads();
        int lim = min(16, deg - base);
        for (int j = 0; j < lim; ++j)
            acc += lal[j][h] * xh_b[(size_t)lsrc[j] * HID + tid];
        __syncthreads();
    }
    gout[(size_t)b * HID + tid] = acc;
}

// fused per-node pipeline, coalesced transposed-weight access
__global__ __launch_bounds__(128) void k_node(
        const float* __restrict__ gout, const float* __restrict__ b_gat,
        const float* __restrict__ g1, const float* __restrict__ be1,
        const float* __restrict__ WTq, const float* __restrict__ b_qkv,
        const float* __restrict__ WoT, const float* __restrict__ b_o,
        const float* __restrict__ g2, const float* __restrict__ be2,
        const float* __restrict__ noise,
        const float* __restrict__ Wc1, const float* __restrict__ bc1,
        const float* __restrict__ gc, const float* __restrict__ bec,
        const float* __restrict__ Wc2, const float* __restrict__ bc2,
        float* __restrict__ out) {
    __shared__ float nf[T][HID];
    __shared__ float nrm[T][HID];
    __shared__ float ql[HID];
    __shared__ float kl[H][T][D];
    __shared__ float vl[H][T][D];
    __shared__ float attn_l[H][T];
    __shared__ float ta[HID];
    __shared__ float red[128];
    __shared__ float emb_l[HID];
    __shared__ float h1_l[HID];
    __shared__ float mu1[T], rs1[T];

    int n = blockIdx.x;
    int tid = threadIdx.x;

    for (int idx = tid; idx < T * HID; idx += 128) {
        int t = idx >> 7, c = idx & 127;
        nf[t][c] = gout[(size_t)(t * N + n) * HID + c] + b_gat[c];
    }
    __syncthreads();

    if (tid < T) {
        float p = 0.0f;
        for (int c = 0; c < HID; ++c) p += nf[tid][c];
        float mu = p * (1.0f / HID);
        float v = 0.0f;
        for (int c = 0; c < HID; ++c) { float dd = nf[tid][c] - mu; v += dd * dd; }
        mu1[tid] = mu;
        rs1[tid] = rsqrtf(v * (1.0f / HID) + 1e-5f);
    }
    __syncthreads();
    for (int idx = tid; idx < T * HID; idx += 128) {
        int t = idx >> 7, c = idx & 127;
        nrm[t][c] = (nf[t][c] - mu1[t]) * rs1[t] * g1[c] + be1[c];
    }
    __syncthreads();

    // k and v: thread = output column, t-batched accumulators, coalesced WTq
    {
        int hh = tid >> 4, dd = tid & 15;
        for (int which = 0; which < 2; ++which) {
            int j = (1 + which) * HID + tid;
            float b = b_qkv[j];
            float acc[T];
            #pragma unroll
            for (int tt = 0; tt < T; ++tt) acc[tt] = b;
            for (int c = 0; c < HID; c += 4) {
                float w0 = WTq[(size_t)(c + 0) * 384 + j];
                float w1 = WTq[(size_t)(c + 1) * 384 + j];
                float w2 = WTq[(size_t)(c + 2) * 384 + j];
                float w3 = WTq[(size_t)(c + 3) * 384 + j];
                #pragma unroll
                for (int tt = 0; tt < T; ++tt) {
                    acc[tt] += nrm[tt][c] * w0 + nrm[tt][c + 1] * w1
                             + nrm[tt][c + 2] * w2 + nrm[tt][c + 3] * w3;
                }
            }
            #pragma unroll
            for (int tt = 0; tt < T; ++tt) {
                if (which == 0) kl[hh][tt][dd] = acc[tt];
                else            vl[hh][tt][dd] = acc[tt];
            }
        }
    }
    {
        int j = tid;
        float acc = b_qkv[j];
        for (int c = 0; c < HID; ++c) acc += nrm[T - 1][c] * WTq[(size_t)c * 384 + j];
        ql[tid] = acc;
    }
    __syncthreads();

    if (tid < H) {
        int hh = tid;
        float sc[T];
        float mx = -1e30f;
        for (int tk = 0; tk < T; ++tk) {
            float a = 0.0f;
            for (int dd = 0; dd < D; ++dd) a += ql[hh * D + dd] * kl[hh][tk][dd];
            a *= 0.25f;
            sc[tk] = a;
            mx = fmaxf(mx, a);
        }
        float ssum = 0.0f;
        for (int tk = 0; tk < T; ++tk) { sc[tk] = expf(sc[tk] - mx); ssum += sc[tk]; }
        float inv = 1.0f / ssum;
        for (int tk = 0; tk < T; ++tk) attn_l[hh][tk] = sc[tk] * inv;
    }
    __syncthreads();

    {
        int c = tid, hh = c >> 4, dd = c & 15;
        float a = 0.0f;
        for (int tk = 0; tk < T; ++tk) a += attn_l[hh][tk] * vl[hh][tk][dd];
        ta[c] = a;
    }
    __syncthreads();

    float o = b_o[tid];
    for (int k = 0; k < HID; ++k) o += ta[k] * WoT[(size_t)k * 128 + tid];
    float x2 = nf[T - 1][tid] + o;

    red[tid] = x2; __syncthreads();
    for (int st = 64; st > 0; st >>= 1) { if (tid < st) red[tid] += red[tid + st]; __syncthreads(); }
    float mu2 = red[0] * (1.0f / HID); __syncthreads();
    float d2 = x2 - mu2;
    red[tid] = d2 * d2; __syncthreads();
    for (int st = 64; st > 0; st >>= 1) { if (tid < st) red[tid] += red[tid + st]; __syncthreads(); }
    float rstd2 = rsqrtf(red[0] * (1.0f / HID) + 1e-5f); __syncthreads();

    float div = sinf(((float)n / (float)N) * 6.28f) * 0.1f;
    float emb = d2 * rstd2 * g2[tid] + be2[tid]
              + div + noise[(size_t)n * HID + tid] * 0.05f;
    emb_l[tid] = emb;
    out[(size_t)n * HID + tid] = emb;
    __syncthreads();

    float h1 = bc1[tid];
    for (int c = 0; c < HID; ++c) h1 += emb_l[c] * Wc1[c * HID + tid];

    red[tid] = h1; __syncthreads();
    for (int st = 64; st > 0; st >>= 1) { if (tid < st) red[tid] += red[tid + st]; __syncthreads(); }
    float mu3 = red[0] * (1.0f / HID); __syncthreads();
    float d3 = h1 - mu3;
    red[tid] = d3 * d3; __syncthreads();
    for (int st = 64; st > 0; st >>= 1) { if (tid < st) red[tid] += red[tid + st]; __syncthreads(); }
    float rstd3 = rsqrtf(red[0] * (1.0f / HID) + 1e-5f); __syncthreads();

    float lnv = d3 * rstd3 * gc[tid] + bec[tid];
    h1_l[tid] = 0.5f * lnv * (1.0f + erff(lnv * 0.70710678118f));
    __syncthreads();

    if (tid < NC) {
        float acc = bc2[tid];
        for (int c = 0; c < HID; ++c) acc += h1_l[c] * Wc2[c * NC + tid];
        if (tid == 1) acc += sinf((float)n * 0.5f) * 0.2f;
        out[(size_t)N * HID + (size_t)n * NC + tid] = acc;
    }
}

extern "C" void kernel_launch(void* const* d_in, const int* in_sizes, int n_in,
                              void* d_out, int out_size, void* d_ws, size_t ws_size,
                              hipStream_t stream) {
    const float* x      = (const float*)d_in[0];
    const int*   ei     = (const int*)d_in[1];
    const float* noise  = (const float*)d_in[2];
    const float* W_proj = (const float*)d_in[3];
    const float* b_proj = (const float*)d_in[4];
    const float* W_gat  = (const float*)d_in[5];
    const float* a_src  = (const float*)d_in[6];
    const float* a_dst  = (const float*)d_in[7];
    const float* b_gat  = (const float*)d_in[8];
    const float* g1     = (const float*)d_in[9];
    const float* be1    = (const float*)d_in[10];
    const float* W_qkv  = (const float*)d_in[11];
    const float* b_qkv  = (const float*)d_in[12];
    const float* W_o    = (const float*)d_in[13];
    const float* b_o    = (const float*)d_in[14];
    const float* g2     = (const float*)d_in[15];
    const float* be2    = (const float*)d_in[16];
    const float* Wc1    = (const float*)d_in[17];
    const float* bc1    = (const float*)d_in[18];
    const float* gc     = (const float*)d_in[19];
    const float* bec    = (const float*)d_in[20];
    const float* Wc2    = (const float*)d_in[21];
    const float* bc2    = (const float*)d_in[22];
    float* out = (float*)d_out;

    float* xh    = (float*)d_ws;                 // 5,120,000
    float* gout  = xh + 5120000;                 // 5,120,000
    float* a_s   = gout + 5120000;               //   320,000
    float* a_d   = a_s + 320000;                 //   320,000
    int*   offs    = (int*)(a_d + 320000);       //    40,008
    int*   cursor  = offs + 40008;               //    40,000
    int*   csr_src = cursor + 40000;             // 1,320,000
    float* WTq   = (float*)(csr_src + 1320000);  //    49,152
    float* WoT   = WTq + 49152;                  //    16,384

    k_tr<<<(384 * 128 + 128 * 128 + 255) / 256, 256, 0, stream>>>(W_qkv, W_o, WTq, WoT);

    k_pg<<<T * N / MT, 256, 0, stream>>>(x, W_proj, b_proj, W_gat, xh);
    k_coef<<<(T * N * H + 255) / 256, 256, 0, stream>>>(xh, a_src, a_dst, a_s, a_d);

    hipMemsetAsync(cursor, 0, 40000 * sizeof(int), stream);
    k_hist<<<(T * EN + 255) / 256, 256, 0, stream>>>(ei, cursor);
    k_scan<<<T, 256, 0, stream>>>(cursor, offs);
    k_scatter<<<(T * EN + 255) / 256, 256, 0, stream>>>(ei, cursor, csr_src);

    k_aggc<<<T * N, 128, 0, stream>>>(offs, csr_src, a_s, a_d, xh, gout);

    k_node<<<N, 128, 0, stream>>>(gout, b_gat, g1, be1, WTq, b_qkv, WoT, b_o,
                                  g2, be2, noise, Wc1, bc1, gc, bec, Wc2, bc2, out);
}

// Round 13
// 482.933 us; speedup vs baseline: 23.6276x; 1.0075x over previous
//
#include <hip/hip_runtime.h>
#include <math.h>

#define T 8
#define N 5000
#define E 160000
#define EN (E + N)
#define IN_DIM 64
#define HID 128
#define H 8
#define D 16
#define NC 2
#define MT 32            // rows per k_pg block

__device__ __forceinline__ float leaky(float e) { return (e >= 0.0f) ? e : 0.2f * e; }

// fused h=relu(x@Wp+bp); xh=h@Wg; a_s/a_d coef epilogue
__global__ __launch_bounds__(256) void k_pg(const float* __restrict__ x,
                                            const float* __restrict__ Wp,
                                            const float* __restrict__ bp,
                                            const float* __restrict__ Wg,
                                            const float* __restrict__ asrc,
                                            const float* __restrict__ adst,
                                            float* __restrict__ xh,
                                            float* __restrict__ a_s,
                                            float* __restrict__ a_d) {
    __shared__ float xt[MT][IN_DIM];        // 8 KB
    __shared__ float ht[MT][HID + 1];       // 16.5 KB (+1 pad)
    int row0 = blockIdx.x * MT;
    int tid = threadIdx.x;

    for (int idx = tid; idx < MT * IN_DIM; idx += 256) {
        int r = idx >> 6, k = idx & 63;
        xt[r][k] = x[(size_t)(row0 + r) * IN_DIM + k];
    }
    __syncthreads();

    int cg = tid & 31;        // cols 4cg..4cg+3
    int rg = tid >> 5;        // rows 4rg..4rg+3
    int c0 = cg * 4, r0 = rg * 4;

    // stage B: h tile
    {
        float4 b4 = *(const float4*)(bp + c0);
        float a00=b4.x,a01=b4.y,a02=b4.z,a03=b4.w;
        float a10=b4.x,a11=b4.y,a12=b4.z,a13=b4.w;
        float a20=b4.x,a21=b4.y,a22=b4.z,a23=b4.w;
        float a30=b4.x,a31=b4.y,a32=b4.z,a33=b4.w;
        for (int k = 0; k < IN_DIM; ++k) {
            float4 w = *(const float4*)(Wp + (size_t)k * HID + c0);
            float x0 = xt[r0 + 0][k], x1 = xt[r0 + 1][k];
            float x2 = xt[r0 + 2][k], x3 = xt[r0 + 3][k];
            a00 += x0*w.x; a01 += x0*w.y; a02 += x0*w.z; a03 += x0*w.w;
            a10 += x1*w.x; a11 += x1*w.y; a12 += x1*w.z; a13 += x1*w.w;
            a20 += x2*w.x; a21 += x2*w.y; a22 += x2*w.z; a23 += x2*w.w;
            a30 += x3*w.x; a31 += x3*w.y; a32 += x3*w.z; a33 += x3*w.w;
        }
        ht[r0+0][c0+0]=fmaxf(a00,0.f); ht[r0+0][c0+1]=fmaxf(a01,0.f);
        ht[r0+0][c0+2]=fmaxf(a02,0.f); ht[r0+0][c0+3]=fmaxf(a03,0.f);
        ht[r0+1][c0+0]=fmaxf(a10,0.f); ht[r0+1][c0+1]=fmaxf(a11,0.f);
        ht[r0+1][c0+2]=fmaxf(a12,0.f); ht[r0+1][c0+3]=fmaxf(a13,0.f);
        ht[r0+2][c0+0]=fmaxf(a20,0.f); ht[r0+2][c0+1]=fmaxf(a21,0.f);
        ht[r0+2][c0+2]=fmaxf(a22,0.f); ht[r0+2][c0+3]=fmaxf(a23,0.f);
        ht[r0+3][c0+0]=fmaxf(a30,0.f); ht[r0+3][c0+1]=fmaxf(a31,0.f);
        ht[r0+3][c0+2]=fmaxf(a32,0.f); ht[r0+3][c0+3]=fmaxf(a33,0.f);
    }
    __syncthreads();

    // stage C: xh tile
    float a00=0,a01=0,a02=0,a03=0, a10=0,a11=0,a12=0,a13=0;
    float a20=0,a21=0,a22=0,a23=0, a30=0,a31=0,a32=0,a33=0;
    for (int k = 0; k < HID; ++k) {
        float4 w = *(const float4*)(Wg + (size_t)k * HID + c0);
        float h0 = ht[r0 + 0][k], h1 = ht[r0 + 1][k];
        float h2 = ht[r0 + 2][k], h3 = ht[r0 + 3][k];
        a00 += h0*w.x; a01 += h0*w.y; a02 += h0*w.z; a03 += h0*w.w;
        a10 += h1*w.x; a11 += h1*w.y; a12 += h1*w.z; a13 += h1*w.w;
        a20 += h2*w.x; a21 += h2*w.y; a22 += h2*w.z; a23 += h2*w.w;
        a30 += h3*w.x; a31 += h3*w.y; a32 += h3*w.z; a33 += h3*w.w;
    }
    {
        float4 v;
        v.x=a00; v.y=a01; v.z=a02; v.w=a03;
        *(float4*)(xh + (size_t)(row0 + r0 + 0) * HID + c0) = v;
        v.x=a10; v.y=a11; v.z=a12; v.w=a13;
        *(float4*)(xh + (size_t)(row0 + r0 + 1) * HID + c0) = v;
        v.x=a20; v.y=a21; v.z=a22; v.w=a23;
        *(float4*)(xh + (size_t)(row0 + r0 + 2) * HID + c0) = v;
        v.x=a30; v.y=a31; v.z=a32; v.w=a33;
        *(float4*)(xh + (size_t)(row0 + r0 + 3) * HID + c0) = v;
    }
    __syncthreads();    // all ht reads done
    ht[r0+0][c0+0]=a00; ht[r0+0][c0+1]=a01; ht[r0+0][c0+2]=a02; ht[r0+0][c0+3]=a03;
    ht[r0+1][c0+0]=a10; ht[r0+1][c0+1]=a11; ht[r0+1][c0+2]=a12; ht[r0+1][c0+3]=a13;
    ht[r0+2][c0+0]=a20; ht[r0+2][c0+1]=a21; ht[r0+2][c0+2]=a22; ht[r0+2][c0+3]=a23;
    ht[r0+3][c0+0]=a30; ht[r0+3][c0+1]=a31; ht[r0+3][c0+2]=a32; ht[r0+3][c0+3]=a33;
    __syncthreads();

    // coef epilogue: r = tid>>3 (0..31), hh = tid&7
    {
        int r = tid >> 3, hh = tid & 7;
        float s1 = 0.0f, s2 = 0.0f;
        #pragma unroll
        for (int d = 0; d < D; ++d) {
            float v = ht[r][hh * D + d];
            s1 += v * asrc[hh * D + d];
            s2 += v * adst[hh * D + d];
        }
        a_s[(size_t)(row0 + r) * H + hh] = s1;
        a_d[(size_t)(row0 + r) * H + hh] = s2;
    }
}

// transpose W_qkv (384x128 -> 128x384) and W_o (128x128 -> 128x128)
__global__ void k_tr(const float* __restrict__ W_qkv, const float* __restrict__ W_o,
                     float* __restrict__ WTq, float* __restrict__ WoT) {
    int idx = blockIdx.x * 256 + threadIdx.x;
    if (idx < 384 * 128) {
        int j = idx >> 7, c = idx & 127;
        WTq[c * 384 + j] = W_qkv[idx];
    } else if (idx < 384 * 128 + 128 * 128) {
        int r = idx - 384 * 128;
        int j = r >> 7, k = r & 127;
        WoT[k * 128 + j] = W_o[r];
    }
}

__device__ __forceinline__ void esd_g(const int* __restrict__ ei, int t, int i,
                                      int& s, int& d) {
    if (i < E) {
        s = ei[(size_t)(2 * t) * E + i];
        d = ei[(size_t)(2 * t + 1) * E + i];
    } else {
        s = d = i - E;
    }
}

__global__ void k_hist(const int* __restrict__ ei, int* __restrict__ cursor) {
    int idx = blockIdx.x * 256 + threadIdx.x;
    if (idx >= T * EN) return;
    int t = idx / EN;
    int i = idx - t * EN;
    int s, d;
    esd_g(ei, t, i, s, d);
    atomicAdd(&cursor[t * N + d], 1);
}

__global__ void k_scan(int* __restrict__ cursor, int* __restrict__ offs) {
    __shared__ int part[256];
    int t = blockIdx.x;
    int tid = threadIdx.x;
    const int CH = 20;
    int begin = tid * CH;
    int sum = 0;
    for (int k = 0; k < CH; ++k) {
        int i = begin + k;
        if (i < N) sum += cursor[t * N + i];
    }
    part[tid] = sum;
    __syncthreads();
    if (tid == 0) {
        int run = 0;
        for (int i = 0; i < 256; ++i) { int v = part[i]; part[i] = run; run += v; }
        offs[t * (N + 1) + N] = run;
    }
    __syncthreads();
    int run = part[tid];
    for (int k = 0; k < CH; ++k) {
        int i = begin + k;
        if (i < N) {
            int cnt = cursor[t * N + i];
            offs[t * (N + 1) + i] = run;
            cursor[t * N + i] = run;
            run += cnt;
        }
    }
}

__global__ void k_scatter(const int* __restrict__ ei, int* __restrict__ cursor,
                          int* __restrict__ csr_src) {
    int idx = blockIdx.x * 256 + threadIdx.x;
    if (idx >= T * EN) return;
    int t = idx / EN;
    int i = idx - t * EN;
    int s, d;
    esd_g(ei, t, i, s, d);
    int pos = atomicAdd(&cursor[t * N + d], 1);
    csr_src[(size_t)t * EN + pos] = s;
}

// GAT softmax + aggregation, one block per (t,dst), atomic-free
__global__ __launch_bounds__(128) void k_aggc(
        const int* __restrict__ offs, const int* __restrict__ csr_src,
        const float* __restrict__ a_s, const float* __restrict__ a_d,
        const float* __restrict__ xh, float* __restrict__ gout) {
    int b = blockIdx.x;                  // t*N + dst
    int t = b / N;
    int dst = b - t * N;
    int tid = threadIdx.x;

    int o0 = offs[t * (N + 1) + dst];
    int o1 = offs[t * (N + 1) + dst + 1];
    int deg = o1 - o0;
    const int* esrc = csr_src + (size_t)t * EN + o0;
    const float* as_b = a_s + (size_t)t * N * H;
    const float* ad_b = a_d + (size_t)t * N * H;
    const float* xh_b = xh + (size_t)t * N * HID;

    __shared__ float lm[H][16], ls[H][16];
    __shared__ float fm[H], finv[H];
    __shared__ float lal[16][H];
    __shared__ int   lsrc[16];

    {
        int ha = tid & 7, l = tid >> 3;
        float ad_h = ad_b[dst * H + ha];
        float m = -1e30f, ssum = 0.0f;
        for (int i = l; i < deg; i += 16) {
            int src = esrc[i];
            float e = leaky(as_b[src * H + ha] + ad_h);
            if (e > m) { ssum = ssum * expf(m - e) + 1.0f; m = e; }
            else       { ssum += expf(e - m); }
        }
        lm[ha][l] = m;
        ls[ha][l] = ssum;
    }
    __syncthreads();
    if (tid < H) {
        float mm = -1e30f;
        for (int l = 0; l < 16; ++l) mm = fmaxf(mm, lm[tid][l]);
        float ss = 0.0f;
        for (int l = 0; l < 16; ++l) ss += ls[tid][l] * expf(lm[tid][l] - mm);
        fm[tid] = mm;
        finv[tid] = 1.0f / (ss + 1e-16f);
    }
    __syncthreads();

    int h = tid >> 4;
    int eh_e = tid >> 3, eh_h = tid & 7;
    float acc = 0.0f;
    for (int base = 0; base < deg; base += 16) {
        int ej = base + eh_e;
        if (ej < deg) {
            int src = esrc[ej];
            if (eh_h == 0) lsrc[eh_e] = src;
            float e = leaky(as_b[src * H + eh_h] + ad_b[dst * H + eh_h]);
            lal[eh_e][eh_h] = expf(e - fm[eh_h]) * finv[eh_h];
        }
        __syncthreads();
        int lim = min(16, deg - base);
        for (int j = 0; j < lim; ++j)
            acc += lal[j][h] * xh_b[(size_t)lsrc[j] * HID + tid];
        __syncthreads();
    }
    gout[(size_t)b * HID + tid] = acc;
}

// fused per-node pipeline: 256 threads, k/v computed by parallel thread-groups
__global__ __launch_bounds__(256) void k_node(
        const float* __restrict__ gout, const float* __restrict__ b_gat,
        const float* __restrict__ g1, const float* __restrict__ be1,
        const float* __restrict__ WTq, const float* __restrict__ b_qkv,
        const float* __restrict__ WoT, const float* __restrict__ b_o,
        const float* __restrict__ g2, const float* __restrict__ be2,
        const float* __restrict__ noise,
        const float* __restrict__ Wc1, const float* __restrict__ bc1,
        const float* __restrict__ gc, const float* __restrict__ bec,
        const float* __restrict__ Wc2, const float* __restrict__ bc2,
        float* __restrict__ out) {
    __shared__ float nrm[T][HID];    // nf then normalized, in place
    __shared__ float xlast[HID];     // raw nf[T-1] for residual
    __shared__ float ql[HID];
    __shared__ float kl[H][T][D];
    __shared__ float vl[H][T][D];
    __shared__ float attn_l[H][T];
    __shared__ float ta[HID];
    __shared__ float red[128];
    __shared__ float emb_l[HID];
    __shared__ float h1_l[HID];
    __shared__ float mu1[T], rs1[T];

    int n = blockIdx.x;
    int tid = threadIdx.x;

    // load nf
    for (int i = tid; i < T * HID; i += 256) {
        int t = i >> 7, c = i & 127;
        nrm[t][c] = gout[(size_t)(t * N + n) * HID + c] + b_gat[c];
    }
    __syncthreads();

    // LN1 stats: 16 lanes per row, shuffle reduce
    if (tid < 128) {
        int row = tid >> 4, j = tid & 15;
        float p = 0.0f;
        #pragma unroll
        for (int k = 0; k < 8; ++k) p += nrm[row][j + 16 * k];
        #pragma unroll
        for (int m = 1; m < 16; m <<= 1) p += __shfl_xor(p, m);
        float mu = p * (1.0f / HID);
        float v = 0.0f;
        #pragma unroll
        for (int k = 0; k < 8; ++k) { float d = nrm[row][j + 16 * k] - mu; v += d * d; }
        #pragma unroll
        for (int m = 1; m < 16; m <<= 1) v += __shfl_xor(v, m);
        if (j == 0) { mu1[row] = mu; rs1[row] = rsqrtf(v * (1.0f / HID) + 1e-5f); }
    }
    __syncthreads();

    // normalize in place; stash raw last row
    for (int i = tid; i < T * HID; i += 256) {
        int t = i >> 7, c = i & 127;
        float raw = nrm[t][c];
        if (t == T - 1) xlast[c] = raw;
        nrm[t][c] = (raw - mu1[t]) * rs1[t] * g1[c] + be1[c];
    }
    __syncthreads();

    // k (group 0) / v (group 1) in parallel; q by group 0 afterwards
    {
        int grp = tid >> 7;              // 0: k, 1: v
        int col = tid & 127;
        int hh = col >> 4, dd = col & 15;
        int j = (1 + grp) * HID + col;
        float b = b_qkv[j];
        float acc[T];
        #pragma unroll
        for (int tt = 0; tt < T; ++tt) acc[tt] = b;
        for (int c = 0; c < HID; c += 4) {
            float w0 = WTq[(size_t)(c + 0) * 384 + j];
            float w1 = WTq[(size_t)(c + 1) * 384 + j];
            float w2 = WTq[(size_t)(c + 2) * 384 + j];
            float w3 = WTq[(size_t)(c + 3) * 384 + j];
            #pragma unroll
            for (int tt = 0; tt < T; ++tt) {
                float4 nv = *(const float4*)&nrm[tt][c];
                acc[tt] += nv.x * w0 + nv.y * w1 + nv.z * w2 + nv.w * w3;
            }
        }
        #pragma unroll
        for (int tt = 0; tt < T; ++tt) {
            if (grp == 0) kl[hh][tt][dd] = acc[tt];
            else          vl[hh][tt][dd] = acc[tt];
        }
        if (grp == 0) {                  // q at t = T-1
            float accq = b_qkv[col];
            for (int c = 0; c < HID; c += 4) {
                float4 nv = *(const float4*)&nrm[T - 1][c];
                accq += nv.x * WTq[(size_t)(c + 0) * 384 + col]
                      + nv.y * WTq[(size_t)(c + 1) * 384 + col]
                      + nv.z * WTq[(size_t)(c + 2) * 384 + col]
                      + nv.w * WTq[(size_t)(c + 3) * 384 + col];
            }
            ql[col] = accq;
        }
    }
    __syncthreads();

    if (tid < H) {
        int hh = tid;
        float sc[T];
        float mx = -1e30f;
        #pragma unroll
        for (int tk = 0; tk < T; ++tk) {
            float a = 0.0f;
            #pragma unroll
            for (int dd = 0; dd < D; ++dd) a += ql[hh * D + dd] * kl[hh][tk][dd];
            a *= 0.25f;
            sc[tk] = a;
            mx = fmaxf(mx, a);
        }
        float ssum = 0.0f;
        #pragma unroll
        for (int tk = 0; tk < T; ++tk) { sc[tk] = expf(sc[tk] - mx); ssum += sc[tk]; }
        float inv = 1.0f / ssum;
        #pragma unroll
        for (int tk = 0; tk < T; ++tk) attn_l[hh][tk] = sc[tk] * inv;
    }
    __syncthreads();

    if (tid < 128) {
        int c = tid, hh = c >> 4, dd = c & 15;
        float a = 0.0f;
        #pragma unroll
        for (int tk = 0; tk < T; ++tk) a += attn_l[hh][tk] * vl[hh][tk][dd];
        ta[c] = a;
    }
    __syncthreads();

    // W_o + residual (tid<128), float4 LDS
    float x2 = 0.0f;
    if (tid < 128) {
        float o = b_o[tid];
        for (int k = 0; k < HID; k += 4) {
            float4 t4 = *(const float4*)&ta[k];
            o += t4.x * WoT[(size_t)(k + 0) * 128 + tid]
               + t4.y * WoT[(size_t)(k + 1) * 128 + tid]
               + t4.z * WoT[(size_t)(k + 2) * 128 + tid]
               + t4.w * WoT[(size_t)(k + 3) * 128 + tid];
        }
        x2 = xlast[tid] + o;
        red[tid] = x2;
    }
    __syncthreads();
    if (tid < 64) {
        float s = red[tid] + red[tid + 64];
        #pragma unroll
        for (int m = 1; m < 64; m <<= 1) s += __shfl_xor(s, m);
        if (tid == 0) red[0] = s;
    }
    __syncthreads();
    float mu2 = red[0] * (1.0f / HID);
    __syncthreads();
    float d2 = x2 - mu2;
    if (tid < 128) red[tid] = d2 * d2;
    __syncthreads();
    if (tid < 64) {
        float s = red[tid] + red[tid + 64];
        #pragma unroll
        for (int m = 1; m < 64; m <<= 1) s += __shfl_xor(s, m);
        if (tid == 0) red[0] = s;
    }
    __syncthreads();
    float rstd2 = rsqrtf(red[0] * (1.0f / HID) + 1e-5f);
    __syncthreads();

    if (tid < 128) {
        float div = sinf(((float)n / (float)N) * 6.28f) * 0.1f;
        float emb = d2 * rstd2 * g2[tid] + be2[tid]
                  + div + noise[(size_t)n * HID + tid] * 0.05f;
        emb_l[tid] = emb;
        out[(size_t)n * HID + tid] = emb;
    }
    __syncthreads();

    // classifier h1 = emb @ Wc1 + bc1 (tid<128), float4 LDS
    float h1 = 0.0f;
    if (tid < 128) {
        h1 = bc1[tid];
        for (int c = 0; c < HID; c += 4) {
            float4 e4 = *(const float4*)&emb_l[c];
            h1 += e4.x * Wc1[(size_t)(c + 0) * 128 + tid]
                + e4.y * Wc1[(size_t)(c + 1) * 128 + tid]
                + e4.z * Wc1[(size_t)(c + 2) * 128 + tid]
                + e4.w * Wc1[(size_t)(c + 3) * 128 + tid];
        }
        red[tid] = h1;
    }
    __syncthreads();
    if (tid < 64) {
        float s = red[tid] + red[tid + 64];
        #pragma unroll
        for (int m = 1; m < 64; m <<= 1) s += __shfl_xor(s, m);
        if (tid == 0) red[0] = s;
    }
    __syncthreads();
    float mu3 = red[0] * (1.0f / HID);
    __syncthreads();
    float d3 = h1 - mu3;
    if (tid < 128) red[tid] = d3 * d3;
    __syncthreads();
    if (tid < 64) {
        float s = red[tid] + red[tid + 64];
        #pragma unroll
        for (int m = 1; m < 64; m <<= 1) s += __shfl_xor(s, m);
        if (tid == 0) red[0] = s;
    }
    __syncthreads();
    float rstd3 = rsqrtf(red[0] * (1.0f / HID) + 1e-5f);
    __syncthreads();

    if (tid < 128) {
        float lnv = d3 * rstd3 * gc[tid] + bec[tid];
        h1_l[tid] = 0.5f * lnv * (1.0f + erff(lnv * 0.70710678118f));
    }
    __syncthreads();

    // logits: wave0 -> logit 0, wave1 -> logit 1 (64-lane reduce)
    if (tid < 128) {
        int j = tid >> 6, lane = tid & 63;
        float p = h1_l[lane] * Wc2[lane * NC + j]
                + h1_l[lane + 64] * Wc2[(lane + 64) * NC + j];
        #pragma unroll
        for (int m = 1; m < 64; m <<= 1) p += __shfl_xor(p, m);
        if (lane == 0) {
            float acc = p + bc2[j];
            if (j == 1) acc += sinf((float)n * 0.5f) * 0.2f;
            out[(size_t)N * HID + (size_t)n * NC + j] = acc;
        }
    }
}

extern "C" void kernel_launch(void* const* d_in, const int* in_sizes, int n_in,
                              void* d_out, int out_size, void* d_ws, size_t ws_size,
                              hipStream_t stream) {
    const float* x      = (const float*)d_in[0];
    const int*   ei     = (const int*)d_in[1];
    const float* noise  = (const float*)d_in[2];
    const float* W_proj = (const float*)d_in[3];
    const float* b_proj = (const float*)d_in[4];
    const float* W_gat  = (const float*)d_in[5];
    const float* a_src  = (const float*)d_in[6];
    const float* a_dst  = (const float*)d_in[7];
    const float* b_gat  = (const float*)d_in[8];
    const float* g1     = (const float*)d_in[9];
    const float* be1    = (const float*)d_in[10];
    const float* W_qkv  = (const float*)d_in[11];
    const float* b_qkv  = (const float*)d_in[12];
    const float* W_o    = (const float*)d_in[13];
    const float* b_o    = (const float*)d_in[14];
    const float* g2     = (const float*)d_in[15];
    const float* be2    = (const float*)d_in[16];
    const float* Wc1    = (const float*)d_in[17];
    const float* bc1    = (const float*)d_in[18];
    const float* gc     = (const float*)d_in[19];
    const float* bec    = (const float*)d_in[20];
    const float* Wc2    = (const float*)d_in[21];
    const float* bc2    = (const float*)d_in[22];
    float* out = (float*)d_out;

    float* xh    = (float*)d_ws;                 // 5,120,000
    float* gout  = xh + 5120000;                 // 5,120,000
    float* a_s   = gout + 5120000;               //   320,000
    float* a_d   = a_s + 320000;                 //   320,000
    int*   offs    = (int*)(a_d + 320000);       //    40,008
    int*   cursor  = offs + 40008;               //    40,000
    int*   csr_src = cursor + 40000;             // 1,320,000
    float* WTq   = (float*)(csr_src + 1320000);  //    49,152
    float* WoT   = WTq + 49152;                  //    16,384

    k_tr<<<(384 * 128 + 128 * 128 + 255) / 256, 256, 0, stream>>>(W_qkv, W_o, WTq, WoT);

    k_pg<<<T * N / MT, 256, 0, stream>>>(x, W_proj, b_proj, W_gat, a_src, a_dst,
                                         xh, a_s, a_d);

    hipMemsetAsync(cursor, 0, 40000 * sizeof(int), stream);
    k_hist<<<(T * EN + 255) / 256, 256, 0, stream>>>(ei, cursor);
    k_scan<<<T, 256, 0, stream>>>(cursor, offs);
    k_scatter<<<(T * EN + 255) / 256, 256, 0, stream>>>(ei, cursor, csr_src);

    k_aggc<<<T * N, 128, 0, stream>>>(offs, csr_src, a_s, a_d, xh, gout);

    k_node<<<N, 256, 0, stream>>>(gout, b_gat, g1, be1, WTq, b_qkv, WoT, b_o,
                                  g2, be2, noise, Wc1, bc1, gc, bec, Wc2, bc2, out);
}

// Round 14
// 471.160 us; speedup vs baseline: 24.2180x; 1.0250x over previous
//
#include <hip/hip_runtime.h>
#include <math.h>

#define T 8
#define N 5000
#define E 160000
#define EN (E + N)
#define IN_DIM 64
#define HID 128
#define H 8
#define D 16
#define NC 2
#define MT 32            // rows per k_pg / k_cls block

__device__ __forceinline__ float leaky(float e) { return (e >= 0.0f) ? e : 0.2f * e; }

// fused h=relu(x@Wp+bp); xh=h@Wg; a_s/a_d coef epilogue
__global__ __launch_bounds__(256) void k_pg(const float* __restrict__ x,
                                            const float* __restrict__ Wp,
                                            const float* __restrict__ bp,
                                            const float* __restrict__ Wg,
                                            const float* __restrict__ asrc,
                                            const float* __restrict__ adst,
                                            float* __restrict__ xh,
                                            float* __restrict__ a_s,
                                            float* __restrict__ a_d) {
    __shared__ float xt[MT][IN_DIM];
    __shared__ float ht[MT][HID + 1];
    int row0 = blockIdx.x * MT;
    int tid = threadIdx.x;

    for (int idx = tid; idx < MT * IN_DIM; idx += 256) {
        int r = idx >> 6, k = idx & 63;
        xt[r][k] = x[(size_t)(row0 + r) * IN_DIM + k];
    }
    __syncthreads();

    int cg = tid & 31;
    int rg = tid >> 5;
    int c0 = cg * 4, r0 = rg * 4;

    {
        float4 b4 = *(const float4*)(bp + c0);
        float a00=b4.x,a01=b4.y,a02=b4.z,a03=b4.w;
        float a10=b4.x,a11=b4.y,a12=b4.z,a13=b4.w;
        float a20=b4.x,a21=b4.y,a22=b4.z,a23=b4.w;
        float a30=b4.x,a31=b4.y,a32=b4.z,a33=b4.w;
        for (int k = 0; k < IN_DIM; ++k) {
            float4 w = *(const float4*)(Wp + (size_t)k * HID + c0);
            float x0 = xt[r0 + 0][k], x1 = xt[r0 + 1][k];
            float x2 = xt[r0 + 2][k], x3 = xt[r0 + 3][k];
            a00 += x0*w.x; a01 += x0*w.y; a02 += x0*w.z; a03 += x0*w.w;
            a10 += x1*w.x; a11 += x1*w.y; a12 += x1*w.z; a13 += x1*w.w;
            a20 += x2*w.x; a21 += x2*w.y; a22 += x2*w.z; a23 += x2*w.w;
            a30 += x3*w.x; a31 += x3*w.y; a32 += x3*w.z; a33 += x3*w.w;
        }
        ht[r0+0][c0+0]=fmaxf(a00,0.f); ht[r0+0][c0+1]=fmaxf(a01,0.f);
        ht[r0+0][c0+2]=fmaxf(a02,0.f); ht[r0+0][c0+3]=fmaxf(a03,0.f);
        ht[r0+1][c0+0]=fmaxf(a10,0.f); ht[r0+1][c0+1]=fmaxf(a11,0.f);
        ht[r0+1][c0+2]=fmaxf(a12,0.f); ht[r0+1][c0+3]=fmaxf(a13,0.f);
        ht[r0+2][c0+0]=fmaxf(a20,0.f); ht[r0+2][c0+1]=fmaxf(a21,0.f);
        ht[r0+2][c0+2]=fmaxf(a22,0.f); ht[r0+2][c0+3]=fmaxf(a23,0.f);
        ht[r0+3][c0+0]=fmaxf(a30,0.f); ht[r0+3][c0+1]=fmaxf(a31,0.f);
        ht[r0+3][c0+2]=fmaxf(a32,0.f); ht[r0+3][c0+3]=fmaxf(a33,0.f);
    }
    __syncthreads();

    float a00=0,a01=0,a02=0,a03=0, a10=0,a11=0,a12=0,a13=0;
    float a20=0,a21=0,a22=0,a23=0, a30=0,a31=0,a32=0,a33=0;
    for (int k = 0; k < HID; ++k) {
        float4 w = *(const float4*)(Wg + (size_t)k * HID + c0);
        float h0 = ht[r0 + 0][k], h1 = ht[r0 + 1][k];
        float h2 = ht[r0 + 2][k], h3 = ht[r0 + 3][k];
        a00 += h0*w.x; a01 += h0*w.y; a02 += h0*w.z; a03 += h0*w.w;
        a10 += h1*w.x; a11 += h1*w.y; a12 += h1*w.z; a13 += h1*w.w;
        a20 += h2*w.x; a21 += h2*w.y; a22 += h2*w.z; a23 += h2*w.w;
        a30 += h3*w.x; a31 += h3*w.y; a32 += h3*w.z; a33 += h3*w.w;
    }
    {
        float4 v;
        v.x=a00; v.y=a01; v.z=a02; v.w=a03;
        *(float4*)(xh + (size_t)(row0 + r0 + 0) * HID + c0) = v;
        v.x=a10; v.y=a11; v.z=a12; v.w=a13;
        *(float4*)(xh + (size_t)(row0 + r0 + 1) * HID + c0) = v;
        v.x=a20; v.y=a21; v.z=a22; v.w=a23;
        *(float4*)(xh + (size_t)(row0 + r0 + 2) * HID + c0) = v;
        v.x=a30; v.y=a31; v.z=a32; v.w=a33;
        *(float4*)(xh + (size_t)(row0 + r0 + 3) * HID + c0) = v;
    }
    __syncthreads();
    ht[r0+0][c0+0]=a00; ht[r0+0][c0+1]=a01; ht[r0+0][c0+2]=a02; ht[r0+0][c0+3]=a03;
    ht[r0+1][c0+0]=a10; ht[r0+1][c0+1]=a11; ht[r0+1][c0+2]=a12; ht[r0+1][c0+3]=a13;
    ht[r0+2][c0+0]=a20; ht[r0+2][c0+1]=a21; ht[r0+2][c0+2]=a22; ht[r0+2][c0+3]=a23;
    ht[r0+3][c0+0]=a30; ht[r0+3][c0+1]=a31; ht[r0+3][c0+2]=a32; ht[r0+3][c0+3]=a33;
    __syncthreads();

    {
        int r = tid >> 3, hh = tid & 7;
        float s1 = 0.0f, s2 = 0.0f;
        #pragma unroll
        for (int d = 0; d < D; ++d) {
            float v = ht[r][hh * D + d];
            s1 += v * asrc[hh * D + d];
            s2 += v * adst[hh * D + d];
        }
        a_s[(size_t)(row0 + r) * H + hh] = s1;
        a_d[(size_t)(row0 + r) * H + hh] = s2;
    }
}

// transpose W_qkv (384x128 -> 128x384) and W_o (128x128 -> 128x128)
__global__ void k_tr(const float* __restrict__ W_qkv, const float* __restrict__ W_o,
                     float* __restrict__ WTq, float* __restrict__ WoT) {
    int idx = blockIdx.x * 256 + threadIdx.x;
    if (idx < 384 * 128) {
        int j = idx >> 7, c = idx & 127;
        WTq[c * 384 + j] = W_qkv[idx];
    } else if (idx < 384 * 128 + 128 * 128) {
        int r = idx - 384 * 128;
        int j = r >> 7, k = r & 127;
        WoT[k * 128 + j] = W_o[r];
    }
}

__device__ __forceinline__ void esd_g(const int* __restrict__ ei, int t, int i,
                                      int& s, int& d) {
    if (i < E) {
        s = ei[(size_t)(2 * t) * E + i];
        d = ei[(size_t)(2 * t + 1) * E + i];
    } else {
        s = d = i - E;
    }
}

__global__ void k_hist(const int* __restrict__ ei, int* __restrict__ cursor) {
    int idx = blockIdx.x * 256 + threadIdx.x;
    if (idx >= T * EN) return;
    int t = idx / EN;
    int i = idx - t * EN;
    int s, d;
    esd_g(ei, t, i, s, d);
    atomicAdd(&cursor[t * N + d], 1);
}

__global__ void k_scan(int* __restrict__ cursor, int* __restrict__ offs) {
    __shared__ int part[256];
    int t = blockIdx.x;
    int tid = threadIdx.x;
    const int CH = 20;
    int begin = tid * CH;
    int sum = 0;
    for (int k = 0; k < CH; ++k) {
        int i = begin + k;
        if (i < N) sum += cursor[t * N + i];
    }
    part[tid] = sum;
    __syncthreads();
    if (tid == 0) {
        int run = 0;
        for (int i = 0; i < 256; ++i) { int v = part[i]; part[i] = run; run += v; }
        offs[t * (N + 1) + N] = run;
    }
    __syncthreads();
    int run = part[tid];
    for (int k = 0; k < CH; ++k) {
        int i = begin + k;
        if (i < N) {
            int cnt = cursor[t * N + i];
            offs[t * (N + 1) + i] = run;
            cursor[t * N + i] = run;
            run += cnt;
        }
    }
}

__global__ void k_scatter(const int* __restrict__ ei, int* __restrict__ cursor,
                          int* __restrict__ csr_src) {
    int idx = blockIdx.x * 256 + threadIdx.x;
    if (idx >= T * EN) return;
    int t = idx / EN;
    int i = idx - t * EN;
    int s, d;
    esd_g(ei, t, i, s, d);
    int pos = atomicAdd(&cursor[t * N + d], 1);
    csr_src[(size_t)t * EN + pos] = s;
}

// GAT softmax + aggregation, one block per (t,dst), atomic-free
__global__ __launch_bounds__(128) void k_aggc(
        const int* __restrict__ offs, const int* __restrict__ csr_src,
        const float* __restrict__ a_s, const float* __restrict__ a_d,
        const float* __restrict__ xh, float* __restrict__ gout) {
    int b = blockIdx.x;
    int t = b / N;
    int dst = b - t * N;
    int tid = threadIdx.x;

    int o0 = offs[t * (N + 1) + dst];
    int o1 = offs[t * (N + 1) + dst + 1];
    int deg = o1 - o0;
    const int* esrc = csr_src + (size_t)t * EN + o0;
    const float* as_b = a_s + (size_t)t * N * H;
    const float* ad_b = a_d + (size_t)t * N * H;
    const float* xh_b = xh + (size_t)t * N * HID;

    __shared__ float lm[H][16], ls[H][16];
    __shared__ float fm[H], finv[H];
    __shared__ float lal[16][H];
    __shared__ int   lsrc[16];

    {
        int ha = tid & 7, l = tid >> 3;
        float ad_h = ad_b[dst * H + ha];
        float m = -1e30f, ssum = 0.0f;
        for (int i = l; i < deg; i += 16) {
            int src = esrc[i];
            float e = leaky(as_b[src * H + ha] + ad_h);
            if (e > m) { ssum = ssum * expf(m - e) + 1.0f; m = e; }
            else       { ssum += expf(e - m); }
        }
        lm[ha][l] = m;
        ls[ha][l] = ssum;
    }
    __syncthreads();
    if (tid < H) {
        float mm = -1e30f;
        for (int l = 0; l < 16; ++l) mm = fmaxf(mm, lm[tid][l]);
        float ss = 0.0f;
        for (int l = 0; l < 16; ++l) ss += ls[tid][l] * expf(lm[tid][l] - mm);
        fm[tid] = mm;
        finv[tid] = 1.0f / (ss + 1e-16f);
    }
    __syncthreads();

    int h = tid >> 4;
    int eh_e = tid >> 3, eh_h = tid & 7;
    float acc = 0.0f;
    for (int base = 0; base < deg; base += 16) {
        int ej = base + eh_e;
        if (ej < deg) {
            int src = esrc[ej];
            if (eh_h == 0) lsrc[eh_e] = src;
            float e = leaky(as_b[src * H + eh_h] + ad_b[dst * H + eh_h]);
            lal[eh_e][eh_h] = expf(e - fm[eh_h]) * finv[eh_h];
        }
        __syncthreads();
        int lim = min(16, deg - base);
        for (int j = 0; j < lim; ++j)
            acc += lal[j][h] * xh_b[(size_t)lsrc[j] * HID + tid];
        __syncthreads();
    }
    gout[(size_t)b * HID + tid] = acc;
}

// per-node: LN1 -> fused k|v|q (pipelined weight prefetch) -> attention
// -> W_o -> LN2 -> emb(+div+noise) -> out
__global__ __launch_bounds__(128) void k_node(
        const float* __restrict__ gout, const float* __restrict__ b_gat,
        const float* __restrict__ g1, const float* __restrict__ be1,
        const float* __restrict__ WTq, const float* __restrict__ b_qkv,
        const float* __restrict__ WoT, const float* __restrict__ b_o,
        const float* __restrict__ g2, const float* __restrict__ be2,
        const float* __restrict__ noise, float* __restrict__ out) {
    __shared__ float nrm[T][HID];
    __shared__ float xlast[HID];
    __shared__ float ql[HID];
    __shared__ float kl[H][T][D];
    __shared__ float vl[H][T][D];
    __shared__ float attn_l[H][T];
    __shared__ float ta[HID];
    __shared__ float red[128];
    __shared__ float mu1[T], rs1[T];

    int n = blockIdx.x;
    int tid = threadIdx.x;

    for (int i = tid; i < T * HID; i += 128) {
        int t = i >> 7, c = i & 127;
        nrm[t][c] = gout[(size_t)(t * N + n) * HID + c] + b_gat[c];
    }
    __syncthreads();

    // LN1: 16 lanes per row
    {
        int row = tid >> 4, j = tid & 15;
        float p = 0.0f;
        #pragma unroll
        for (int k = 0; k < 8; ++k) p += nrm[row][j + 16 * k];
        #pragma unroll
        for (int m = 1; m < 16; m <<= 1) p += __shfl_xor(p, m);
        float mu = p * (1.0f / HID);
        float v = 0.0f;
        #pragma unroll
        for (int k = 0; k < 8; ++k) { float d = nrm[row][j + 16 * k] - mu; v += d * d; }
        #pragma unroll
        for (int m = 1; m < 16; m <<= 1) v += __shfl_xor(v, m);
        if (j == 0) { mu1[row] = mu; rs1[row] = rsqrtf(v * (1.0f / HID) + 1e-5f); }
    }
    __syncthreads();

    for (int i = tid; i < T * HID; i += 128) {
        int t = i >> 7, c = i & 127;
        float raw = nrm[t][c];
        if (t == T - 1) xlast[c] = raw;
        nrm[t][c] = (raw - mu1[t]) * rs1[t] * g1[c] + be1[c];
    }
    __syncthreads();

    // fused k|v|q GEMM, two-bank software-pipelined weight prefetch
    {
        int jk = HID + tid, jv = 2 * HID + tid;
        float ka[T], va[T];
        float bk = b_qkv[jk], bv = b_qkv[jv];
        #pragma unroll
        for (int tt = 0; tt < T; ++tt) { ka[tt] = bk; va[tt] = bv; }
        float qa = b_qkv[tid];

        float wk0[4], wv0[4], wq0[4], wk1[4], wv1[4], wq1[4];
        #pragma unroll
        for (int i = 0; i < 4; ++i) {
            wk0[i] = WTq[(size_t)i * 384 + jk];
            wv0[i] = WTq[(size_t)i * 384 + jv];
            wq0[i] = WTq[(size_t)i * 384 + tid];
        }
        for (int c = 0; c < HID; c += 8) {
            #pragma unroll
            for (int i = 0; i < 4; ++i) {
                wk1[i] = WTq[(size_t)(c + 4 + i) * 384 + jk];
                wv1[i] = WTq[(size_t)(c + 4 + i) * 384 + jv];
                wq1[i] = WTq[(size_t)(c + 4 + i) * 384 + tid];
            }
            #pragma unroll
            for (int tt = 0; tt < T; ++tt) {
                float4 nv = *(const float4*)&nrm[tt][c];
                ka[tt] += nv.x*wk0[0] + nv.y*wk0[1] + nv.z*wk0[2] + nv.w*wk0[3];
                va[tt] += nv.x*wv0[0] + nv.y*wv0[1] + nv.z*wv0[2] + nv.w*wv0[3];
                if (tt == T - 1)
                    qa += nv.x*wq0[0] + nv.y*wq0[1] + nv.z*wq0[2] + nv.w*wq0[3];
            }
            if (c + 8 < HID) {
                #pragma unroll
                for (int i = 0; i < 4; ++i) {
                    wk0[i] = WTq[(size_t)(c + 8 + i) * 384 + jk];
                    wv0[i] = WTq[(size_t)(c + 8 + i) * 384 + jv];
                    wq0[i] = WTq[(size_t)(c + 8 + i) * 384 + tid];
                }
            }
            #pragma unroll
            for (int tt = 0; tt < T; ++tt) {
                float4 nv = *(const float4*)&nrm[tt][c + 4];
                ka[tt] += nv.x*wk1[0] + nv.y*wk1[1] + nv.z*wk1[2] + nv.w*wk1[3];
                va[tt] += nv.x*wv1[0] + nv.y*wv1[1] + nv.z*wv1[2] + nv.w*wv1[3];
                if (tt == T - 1)
                    qa += nv.x*wq1[0] + nv.y*wq1[1] + nv.z*wq1[2] + nv.w*wq1[3];
            }
        }
        int hh = tid >> 4, dd = tid & 15;
        #pragma unroll
        for (int tt = 0; tt < T; ++tt) {
            kl[hh][tt][dd] = ka[tt];
            vl[hh][tt][dd] = va[tt];
        }
        ql[tid] = qa;
    }
    __syncthreads();

    if (tid < H) {
        int hh = tid;
        float sc[T];
        float mx = -1e30f;
        #pragma unroll
        for (int tk = 0; tk < T; ++tk) {
            float a = 0.0f;
            #pragma unroll
            for (int dd = 0; dd < D; ++dd) a += ql[hh * D + dd] * kl[hh][tk][dd];
            a *= 0.25f;
            sc[tk] = a;
            mx = fmaxf(mx, a);
        }
        float ssum = 0.0f;
        #pragma unroll
        for (int tk = 0; tk < T; ++tk) { sc[tk] = expf(sc[tk] - mx); ssum += sc[tk]; }
        float inv = 1.0f / ssum;
        #pragma unroll
        for (int tk = 0; tk < T; ++tk) attn_l[hh][tk] = sc[tk] * inv;
    }
    __syncthreads();

    {
        int hh = tid >> 4, dd = tid & 15;
        float a = 0.0f;
        #pragma unroll
        for (int tk = 0; tk < T; ++tk) a += attn_l[hh][tk] * vl[hh][tk][dd];
        ta[tid] = a;
    }
    __syncthreads();

    // W_o + residual
    float o = b_o[tid];
    #pragma unroll 8
    for (int k = 0; k < HID; k += 4) {
        float4 t4 = *(const float4*)&ta[k];
        o += t4.x * WoT[(size_t)(k + 0) * 128 + tid]
           + t4.y * WoT[(size_t)(k + 1) * 128 + tid]
           + t4.z * WoT[(size_t)(k + 2) * 128 + tid]
           + t4.w * WoT[(size_t)(k + 3) * 128 + tid];
    }
    float x2 = xlast[tid] + o;

    red[tid] = x2;
    __syncthreads();
    if (tid < 64) {
        float s = red[tid] + red[tid + 64];
        #pragma unroll
        for (int m = 1; m < 64; m <<= 1) s += __shfl_xor(s, m);
        if (tid == 0) red[0] = s;
    }
    __syncthreads();
    float mu2 = red[0] * (1.0f / HID);
    __syncthreads();
    float d2 = x2 - mu2;
    red[tid] = d2 * d2;
    __syncthreads();
    if (tid < 64) {
        float s = red[tid] + red[tid + 64];
        #pragma unroll
        for (int m = 1; m < 64; m <<= 1) s += __shfl_xor(s, m);
        if (tid == 0) red[0] = s;
    }
    __syncthreads();
    float rstd2 = rsqrtf(red[0] * (1.0f / HID) + 1e-5f);

    float div = sinf(((float)n / (float)N) * 6.28f) * 0.1f;
    float emb = d2 * rstd2 * g2[tid] + be2[tid]
              + div + noise[(size_t)n * HID + tid] * 0.05f;
    out[(size_t)n * HID + tid] = emb;
}

// classifier: tiled h1 = emb@Wc1 + bc1 -> LN3 -> gelu -> logits
__global__ __launch_bounds__(256) void k_cls(const float* __restrict__ emb,
                                             const float* __restrict__ Wc1,
                                             const float* __restrict__ bc1,
                                             const float* __restrict__ gc,
                                             const float* __restrict__ bec,
                                             const float* __restrict__ Wc2,
                                             const float* __restrict__ bc2,
                                             float* __restrict__ out) {
    __shared__ float et[MT][HID];
    __shared__ float h1t[MT][HID + 1];
    int row0 = blockIdx.x * MT;
    int tid = threadIdx.x;

    for (int idx = tid; idx < MT * HID; idx += 256) {
        int r = idx >> 7, c = idx & 127;
        int row = row0 + r;
        et[r][c] = (row < N) ? emb[(size_t)row * HID + c] : 0.0f;
    }
    __syncthreads();

    {
        int cg = tid & 31, rg = tid >> 5;
        int c0 = cg * 4, r0 = rg * 4;
        float4 b4 = *(const float4*)(bc1 + c0);
        float a00=b4.x,a01=b4.y,a02=b4.z,a03=b4.w;
        float a10=b4.x,a11=b4.y,a12=b4.z,a13=b4.w;
        float a20=b4.x,a21=b4.y,a22=b4.z,a23=b4.w;
        float a30=b4.x,a31=b4.y,a32=b4.z,a33=b4.w;
        for (int k = 0; k < HID; ++k) {
            float4 w = *(const float4*)(Wc1 + (size_t)k * HID + c0);
            float e0 = et[r0 + 0][k], e1 = et[r0 + 1][k];
            float e2 = et[r0 + 2][k], e3 = et[r0 + 3][k];
            a00 += e0*w.x; a01 += e0*w.y; a02 += e0*w.z; a03 += e0*w.w;
            a10 += e1*w.x; a11 += e1*w.y; a12 += e1*w.z; a13 += e1*w.w;
            a20 += e2*w.x; a21 += e2*w.y; a22 += e2*w.z; a23 += e2*w.w;
            a30 += e3*w.x; a31 += e3*w.y; a32 += e3*w.z; a33 += e3*w.w;
        }
        h1t[r0+0][c0+0]=a00; h1t[r0+0][c0+1]=a01; h1t[r0+0][c0+2]=a02; h1t[r0+0][c0+3]=a03;
        h1t[r0+1][c0+0]=a10; h1t[r0+1][c0+1]=a11; h1t[r0+1][c0+2]=a12; h1t[r0+1][c0+3]=a13;
        h1t[r0+2][c0+0]=a20; h1t[r0+2][c0+1]=a21; h1t[r0+2][c0+2]=a22; h1t[r0+2][c0+3]=a23;
        h1t[r0+3][c0+0]=a30; h1t[r0+3][c0+1]=a31; h1t[r0+3][c0+2]=a32; h1t[r0+3][c0+3]=a33;
    }
    __syncthreads();

    // LN3 + gelu: 8 lanes per row (32 rows x 8 = 256 threads)
    {
        int r = tid >> 3, l = tid & 7;
        float p = 0.0f;
        #pragma unroll
        for (int k = 0; k < 16; ++k) p += h1t[r][l + 8 * k];
        #pragma unroll
        for (int m = 1; m < 8; m <<= 1) p += __shfl_xor(p, m);
        float mu = p * (1.0f / HID);
        float v = 0.0f;
        #pragma unroll
        for (int k = 0; k < 16; ++k) { float d = h1t[r][l + 8 * k] - mu; v += d * d; }
        #pragma unroll
        for (int m = 1; m < 8; m <<= 1) v += __shfl_xor(v, m);
        float rstd = rsqrtf(v * (1.0f / HID) + 1e-5f);
        #pragma unroll
        for (int k = 0; k < 16; ++k) {
            int c = l + 8 * k;
            float lnv = (h1t[r][c] - mu) * rstd * gc[c] + bec[c];
            h1t[r][c] = 0.5f * lnv * (1.0f + erff(lnv * 0.70710678118f));
        }
    }
    __syncthreads();

    // logits: 64 outputs (32 rows x 2)
    if (tid < MT * NC) {
        int r = tid >> 1, j = tid & 1;
        int row = row0 + r;
        if (row < N) {
            float acc = bc2[j];
            #pragma unroll 8
            for (int c = 0; c < HID; ++c) acc += h1t[r][c] * Wc2[c * NC + j];
            if (j == 1) acc += sinf((float)row * 0.5f) * 0.2f;
            out[(size_t)N * HID + (size_t)row * NC + j] = acc;
        }
    }
}

extern "C" void kernel_launch(void* const* d_in, const int* in_sizes, int n_in,
                              void* d_out, int out_size, void* d_ws, size_t ws_size,
                              hipStream_t stream) {
    const float* x      = (const float*)d_in[0];
    const int*   ei     = (const int*)d_in[1];
    const float* noise  = (const float*)d_in[2];
    const float* W_proj = (const float*)d_in[3];
    const float* b_proj = (const float*)d_in[4];
    const float* W_gat  = (const float*)d_in[5];
    const float* a_src  = (const float*)d_in[6];
    const float* a_dst  = (const float*)d_in[7];
    const float* b_gat  = (const float*)d_in[8];
    const float* g1     = (const float*)d_in[9];
    const float* be1    = (const float*)d_in[10];
    const float* W_qkv  = (const float*)d_in[11];
    const float* b_qkv  = (const float*)d_in[12];
    const float* W_o    = (const float*)d_in[13];
    const float* b_o    = (const float*)d_in[14];
    const float* g2     = (const float*)d_in[15];
    const float* be2    = (const float*)d_in[16];
    const float* Wc1    = (const float*)d_in[17];
    const float* bc1    = (const float*)d_in[18];
    const float* gc     = (const float*)d_in[19];
    const float* bec    = (const float*)d_in[20];
    const float* Wc2    = (const float*)d_in[21];
    const float* bc2    = (const float*)d_in[22];
    float* out = (float*)d_out;

    float* xh    = (float*)d_ws;                 // 5,120,000
    float* gout  = xh + 5120000;                 // 5,120,000
    float* a_s   = gout + 5120000;               //   320,000
    float* a_d   = a_s + 320000;                 //   320,000
    int*   offs    = (int*)(a_d + 320000);       //    40,008
    int*   cursor  = offs + 40008;               //    40,000
    int*   csr_src = cursor + 40000;             // 1,320,000
    float* WTq   = (float*)(csr_src + 1320000);  //    49,152
    float* WoT   = WTq + 49152;                  //    16,384

    k_tr<<<(384 * 128 + 128 * 128 + 255) / 256, 256, 0, stream>>>(W_qkv, W_o, WTq, WoT);

    k_pg<<<T * N / MT, 256, 0, stream>>>(x, W_proj, b_proj, W_gat, a_src, a_dst,
                                         xh, a_s, a_d);

    hipMemsetAsync(cursor, 0, 40000 * sizeof(int), stream);
    k_hist<<<(T * EN + 255) / 256, 256, 0, stream>>>(ei, cursor);
    k_scan<<<T, 256, 0, stream>>>(cursor, offs);
    k_scatter<<<(T * EN + 255) / 256, 256, 0, stream>>>(ei, cursor, csr_src);

    k_aggc<<<T * N, 128, 0, stream>>>(offs, csr_src, a_s, a_d, xh, gout);

    k_node<<<N, 128, 0, stream>>>(gout, b_gat, g1, be1, WTq, b_qkv, WoT, b_o,
                                  g2, be2, noise, out);

    k_cls<<<(N + MT - 1) / MT, 256, 0, stream>>>(out, Wc1, bc1, gc, bec, Wc2, bc2, out);
}